// Round 1
// baseline (2217.320 us; speedup 1.0000x reference)
//
#include <hip/hip_runtime.h>
#include <hip/hip_bf16.h>
#include <math.h>

#define BB 16
#define NN 2048

// ---------------- K1: h = relu(bn(conv1d(x))) ; xx = ||h||^2 ----------------
__global__ __launch_bounds__(256) void k_h(const float* __restrict__ x,
                                           const float* __restrict__ lw,
                                           const float* __restrict__ ls,
                                           const float* __restrict__ lb,
                                           float* __restrict__ h,
                                           float* __restrict__ xx) {
  int p = blockIdx.x * blockDim.x + threadIdx.x;
  if (p >= BB * NN) return;
  int b = p >> 11;
  int n = p & (NN - 1);
  const float* xb = x + (size_t)b * 3 * NN + n;
  float x0 = xb[0], x1 = xb[NN], x2 = xb[2 * NN];
  float hv[8];
  float ss = 0.f;
#pragma unroll
  for (int o = 0; o < 8; ++o) {
    float v = x0 * lw[o * 3 + 0] + x1 * lw[o * 3 + 1] + x2 * lw[o * 3 + 2];
    v = fmaxf(v * ls[o] + lb[o], 0.f);
    hv[o] = v;
    ss += v * v;  // keep same accumulation order as k_knn's inner product
  }
  float4* hp = (float4*)(h + (size_t)p * 8);
  hp[0] = make_float4(hv[0], hv[1], hv[2], hv[3]);
  hp[1] = make_float4(hv[4], hv[5], hv[6], hv[7]);
  xx[p] = ss;
}

// ---------------- K2: kNN top-16 (covers k=16 and k=12 prefix) ----------------
__global__ __launch_bounds__(64) void k_knn(const float* __restrict__ h,
                                            const float* __restrict__ xx,
                                            int* __restrict__ knn_idx) {
  __shared__ float dist[NN];
  int p = blockIdx.x;
  int b = p >> 11;
  int n = p & (NN - 1);
  int lane = threadIdx.x;
  const float* hb = h + (size_t)b * NN * 8;
  const float4* qp = (const float4*)(hb + (size_t)n * 8);
  float4 q0 = qp[0], q1 = qp[1];
  float xq = xx[p];
  const float* xxb = xx + (size_t)b * NN;
  for (int m = lane; m < NN; m += 64) {
    const float4* ap = (const float4*)(hb + (size_t)m * 8);
    float4 a0 = ap[0], a1 = ap[1];
    float inner = q0.x * a0.x + q0.y * a0.y + q0.z * a0.z + q0.w * a0.w +
                  q1.x * a1.x + q1.y * a1.y + q1.z * a1.z + q1.w * a1.w;
    dist[m] = 2.f * inner - xq - xxb[m];  // neg squared distance; self == 0 exactly
  }
  __syncthreads();
  for (int r = 0; r < 16; ++r) {
    float best = -INFINITY;
    int bi = NN;
    for (int m = lane; m < NN; m += 64) {
      float v = dist[m];
      if (v > best) { best = v; bi = m; }  // ascending m => keeps smallest index on ties
    }
#pragma unroll
    for (int s = 32; s >= 1; s >>= 1) {
      float ov = __shfl_xor(best, s);
      int oi = __shfl_xor(bi, s);
      if (ov > best || (ov == best && oi < bi)) { best = ov; bi = oi; }
    }
    if (lane == 0) {
      knn_idx[(size_t)p * 16 + r] = bi;
      dist[bi] = -INFINITY;
    }
    __syncthreads();
  }
}

// ---------------- K3: fused edge-feat -> conv1 -> conv2 -> att-score -> pool -> att-conv ----------------
// One block: TILE=4 points of one batch. All intermediates in LDS.
template <int K, int FOFF>
__global__ __launch_bounds__(256, 2) void k_branch(
    const float* __restrict__ h, const int* __restrict__ knn_idx,
    const float* __restrict__ w1, const float* __restrict__ s1, const float* __restrict__ b1,
    const float* __restrict__ w2, const float* __restrict__ s2, const float* __restrict__ b2,
    const float* __restrict__ w_att, const float* __restrict__ w_p,
    const float* __restrict__ s_p, const float* __restrict__ b_p,
    float* __restrict__ fout) {
  constexpr int TILE = 4;
  constexpr int R = TILE * K;       // 64 or 48 rows
  __shared__ float e_s[R][20];      // edge features (16) padded
  __shared__ float g1_s[R][68];     // conv1 out (64) padded, 16B-aligned rows
  __shared__ float g2_s[R][132];    // conv2 out (128) padded, 16B-aligned rows
  __shared__ float pool_s[TILE][132];

  int tid = threadIdx.x;
  int pbase = blockIdx.x * TILE;    // global point index base (same b for whole tile)
  int b = pbase >> 11;
  const float* hb = h + (size_t)b * NN * 8;

  // Phase A: build edge features e = [nbr - ctr, ctr]
  if (tid < R) {
    int t = tid / K;
    int j = tid - t * K;
    int p = pbase + t;
    int nloc = p & (NN - 1);
    int id = knn_idx[(size_t)p * 16 + j];
    const float* cp = hb + (size_t)nloc * 8;
    const float* np_ = hb + (size_t)id * 8;
#pragma unroll
    for (int c = 0; c < 8; ++c) {
      float cv = cp[c], nv = np_[c];
      e_s[tid][c] = nv - cv;
      e_s[tid][8 + c] = cv;
    }
  }
  __syncthreads();

  // Phase B: conv1 (16 -> 64) + bn + relu
  {
    int o = tid >> 2, g = tid & 3;
    float w[16];
#pragma unroll
    for (int c = 0; c < 16; ++c) w[c] = w1[o * 16 + c];
    float scl = s1[o], bia = b1[o];
    constexpr int RB = R / 4;
#pragma unroll 1
    for (int i = 0; i < RB; ++i) {
      int r = g * RB + i;
      float a0 = 0.f, a1 = 0.f, a2 = 0.f, a3 = 0.f;
#pragma unroll
      for (int c = 0; c < 4; ++c) {
        a0 += e_s[r][c] * w[c];
        a1 += e_s[r][4 + c] * w[4 + c];
        a2 += e_s[r][8 + c] * w[8 + c];
        a3 += e_s[r][12 + c] * w[12 + c];
      }
      float acc = (a0 + a1) + (a2 + a3);
      g1_s[r][o] = fmaxf(acc * scl + bia, 0.f);
    }
  }
  __syncthreads();

  // Phase C: conv2 (64 -> 128) + bn + relu
  {
    int o = tid >> 1, hf = tid & 1;
    float w[64];
#pragma unroll
    for (int c = 0; c < 64; ++c) w[c] = w2[o * 64 + c];
    float scl = s2[o], bia = b2[o];
    constexpr int RC = R / 2;
#pragma unroll 1
    for (int i = 0; i < RC; ++i) {
      int r = hf * RC + i;
      const float4* row = (const float4*)(&g1_s[r][0]);
      float a0 = 0.f, a1 = 0.f, a2 = 0.f, a3 = 0.f;
#pragma unroll
      for (int c4 = 0; c4 < 16; ++c4) {
        float4 v = row[c4];
        a0 += v.x * w[c4 * 4 + 0];
        a1 += v.y * w[c4 * 4 + 1];
        a2 += v.z * w[c4 * 4 + 2];
        a3 += v.w * w[c4 * 4 + 3];
      }
      float acc = (a0 + a1) + (a2 + a3);
      g2_s[r][o] = fmaxf(acc * scl + bia, 0.f);
    }
  }
  __syncthreads();

  // Phase D: att score (sigmoid of 128x128) + weighted sum over k -> pooled
  {
    int o = tid >> 1, hf = tid & 1;
    float w[128];
#pragma unroll
    for (int c = 0; c < 128; ++c) w[c] = w_att[o * 128 + c];
#pragma unroll 1
    for (int tl = 0; tl < TILE / 2; ++tl) {
      int t = hf * (TILE / 2) + tl;
      float acc = 0.f;
#pragma unroll 1
      for (int j = 0; j < K; ++j) {
        int r = t * K + j;
        const float4* row = (const float4*)(&g2_s[r][0]);
        float a0 = 0.f, a1 = 0.f, a2 = 0.f, a3 = 0.f;
#pragma unroll
        for (int c4 = 0; c4 < 32; ++c4) {
          float4 v = row[c4];
          a0 += v.x * w[c4 * 4 + 0];
          a1 += v.y * w[c4 * 4 + 1];
          a2 += v.z * w[c4 * 4 + 2];
          a3 += v.w * w[c4 * 4 + 3];
        }
        float d = (a0 + a1) + (a2 + a3);
        float sg = 1.f / (1.f + __expf(-d));
        acc += g2_s[r][o] * sg;
      }
      pool_s[t][o] = acc;
    }
  }
  __syncthreads();

  // Phase F: att conv (128 -> 256) + bn + relu, write to f buffer
  {
    float wp[128];
#pragma unroll
    for (int c = 0; c < 128; ++c) wp[c] = w_p[tid * 128 + c];
    float scl = s_p[tid], bia = b_p[tid];
#pragma unroll 1
    for (int u = 0; u < TILE; ++u) {
      const float4* row = (const float4*)(&pool_s[u][0]);
      float a0 = 0.f, a1 = 0.f, a2 = 0.f, a3 = 0.f;
#pragma unroll
      for (int c4 = 0; c4 < 32; ++c4) {
        float4 v = row[c4];
        a0 += v.x * wp[c4 * 4 + 0];
        a1 += v.y * wp[c4 * 4 + 1];
        a2 += v.z * wp[c4 * 4 + 2];
        a3 += v.w * wp[c4 * 4 + 3];
      }
      float acc = (a0 + a1) + (a2 + a3);
      acc = fmaxf(acc * scl + bia, 0.f);
      fout[(size_t)(pbase + u) * 512 + FOFF + tid] = acc;
    }
  }
}

// ---------------- K4: final (B*N,512) @ (512,512)^T + bn + relu, transposed store ----------------
__global__ __launch_bounds__(256) void k_final(const float* __restrict__ f,
                                               const float* __restrict__ wf,
                                               const float* __restrict__ sf,
                                               const float* __restrict__ bfv,
                                               float* __restrict__ out) {
  __shared__ float a_s[64][20];
  __shared__ float b_s[64][20];
  int tid = threadIdx.x;
  int tx = tid & 15, ty = tid >> 4;  // 16 x 16 threads, 4x4 micro-tile each (strided)
  int p0 = blockIdx.x * 64;
  int oc0 = blockIdx.y * 64;
  float acc[4][4];
#pragma unroll
  for (int i = 0; i < 4; ++i)
#pragma unroll
    for (int j = 0; j < 4; ++j) acc[i][j] = 0.f;

  int srow = tid >> 2, sc4 = (tid & 3) * 4;
  for (int kc = 0; kc < 512; kc += 16) {
    float4 av = *(const float4*)(f + (size_t)(p0 + srow) * 512 + kc + sc4);
    float4 bv = *(const float4*)(wf + (size_t)(oc0 + srow) * 512 + kc + sc4);
    __syncthreads();
    *(float4*)(&a_s[srow][sc4]) = av;
    *(float4*)(&b_s[srow][sc4]) = bv;
    __syncthreads();
#pragma unroll
    for (int k4 = 0; k4 < 4; ++k4) {
      float4 a4[4], b4[4];
#pragma unroll
      for (int i = 0; i < 4; ++i) a4[i] = *(const float4*)(&a_s[tx + 16 * i][k4 * 4]);
#pragma unroll
      for (int j = 0; j < 4; ++j) b4[j] = *(const float4*)(&b_s[ty + 16 * j][k4 * 4]);
#pragma unroll
      for (int i = 0; i < 4; ++i)
#pragma unroll
        for (int j = 0; j < 4; ++j) {
          acc[i][j] += a4[i].x * b4[j].x + a4[i].y * b4[j].y +
                       a4[i].z * b4[j].z + a4[i].w * b4[j].w;
        }
    }
  }
  int b = p0 >> 11;
  int n0 = (p0 & (NN - 1)) + tx;
#pragma unroll
  for (int j = 0; j < 4; ++j) {
    int o = oc0 + ty + 16 * j;
    float scl = sf[o], bia = bfv[o];
#pragma unroll
    for (int i = 0; i < 4; ++i) {
      float v = fmaxf(acc[i][j] * scl + bia, 0.f);
      out[((size_t)b * 512 + o) * NN + n0 + 16 * i] = v;
    }
  }
}

extern "C" void kernel_launch(void* const* d_in, const int* in_sizes, int n_in,
                              void* d_out, int out_size, void* d_ws, size_t ws_size,
                              hipStream_t stream) {
  const float* x      = (const float*)d_in[0];
  const float* lw     = (const float*)d_in[1];
  const float* ls     = (const float*)d_in[2];
  const float* lb     = (const float*)d_in[3];
  const float* w1     = (const float*)d_in[4];
  const float* s1     = (const float*)d_in[5];
  const float* b1     = (const float*)d_in[6];
  const float* w2     = (const float*)d_in[7];
  const float* s2     = (const float*)d_in[8];
  const float* b2     = (const float*)d_in[9];
  const float* w3     = (const float*)d_in[10];
  const float* s3     = (const float*)d_in[11];
  const float* b3     = (const float*)d_in[12];
  const float* w4     = (const float*)d_in[13];
  const float* s4     = (const float*)d_in[14];
  const float* b4     = (const float*)d_in[15];
  const float* a1_att = (const float*)d_in[16];
  const float* a1_w   = (const float*)d_in[17];
  const float* a1_s   = (const float*)d_in[18];
  const float* a1_b   = (const float*)d_in[19];
  const float* a2_att = (const float*)d_in[20];
  const float* a2_w   = (const float*)d_in[21];
  const float* a2_s   = (const float*)d_in[22];
  const float* a2_b   = (const float*)d_in[23];
  const float* wf     = (const float*)d_in[24];
  const float* sf     = (const float*)d_in[25];
  const float* bf     = (const float*)d_in[26];
  float* out = (float*)d_out;

  float* ws = (float*)d_ws;
  float* h   = ws;                          // B*N*8 f32
  float* xx  = h + (size_t)BB * NN * 8;     // B*N f32
  int* knn_idx = (int*)(xx + (size_t)BB * NN);        // B*N*16 int32
  float* fbuf  = (float*)(knn_idx + (size_t)BB * NN * 16);  // B*N*512 f32

  k_h<<<dim3((BB * NN + 255) / 256), dim3(256), 0, stream>>>(x, lw, ls, lb, h, xx);
  k_knn<<<dim3(BB * NN), dim3(64), 0, stream>>>(h, xx, knn_idx);
  k_branch<16, 0><<<dim3(BB * NN / 4), dim3(256), 0, stream>>>(
      h, knn_idx, w1, s1, b1, w2, s2, b2, a1_att, a1_w, a1_s, a1_b, fbuf);
  k_branch<12, 256><<<dim3(BB * NN / 4), dim3(256), 0, stream>>>(
      h, knn_idx, w3, s3, b3, w4, s4, b4, a2_att, a2_w, a2_s, a2_b, fbuf);
  k_final<<<dim3(BB * NN / 64, 512 / 64), dim3(256), 0, stream>>>(fbuf, wf, sf, bf, out);
}

// Round 2
// 533.778 us; speedup vs baseline: 4.1540x; 4.1540x over previous
//
#include <hip/hip_runtime.h>
#include <hip/hip_bf16.h>
#include <math.h>

#define BB 16
#define NN 2048

typedef short bf16x8 __attribute__((ext_vector_type(8)));
typedef float f32x4 __attribute__((ext_vector_type(4)));

#define MFMA(a, b, c) __builtin_amdgcn_mfma_f32_16x16x32_bf16(a, b, c, 0, 0, 0)

static __device__ __forceinline__ short f2bf(float f) {
  union { float f; unsigned u; } v; v.f = f;
  unsigned r = v.u + 0x7fffu + ((v.u >> 16) & 1u);
  return (short)(r >> 16);
}
static __device__ __forceinline__ float bf2f(short s) {
  union { unsigned u; float f; } v; v.u = ((unsigned)(unsigned short)s) << 16;
  return v.f;
}

// ---------------- K1: h = relu(bn(conv1d(x))) ; xx = ||h||^2 ----------------
__global__ __launch_bounds__(256) void k_h(const float* __restrict__ x,
                                           const float* __restrict__ lw,
                                           const float* __restrict__ ls,
                                           const float* __restrict__ lb,
                                           float* __restrict__ h,
                                           float* __restrict__ xx) {
  int p = blockIdx.x * blockDim.x + threadIdx.x;
  if (p >= BB * NN) return;
  int b = p >> 11;
  int n = p & (NN - 1);
  const float* xb = x + (size_t)b * 3 * NN + n;
  float x0 = xb[0], x1 = xb[NN], x2 = xb[2 * NN];
  float hv[8];
  float ss = 0.f;
#pragma unroll
  for (int o = 0; o < 8; ++o) {
    float v = x0 * lw[o * 3 + 0] + x1 * lw[o * 3 + 1] + x2 * lw[o * 3 + 2];
    v = fmaxf(v * ls[o] + lb[o], 0.f);
    hv[o] = v;
    ss += v * v;  // same order as k_knn inner product -> self-dist exactly 0
  }
  float4* hp = (float4*)(h + (size_t)p * 8);
  hp[0] = make_float4(hv[0], hv[1], hv[2], hv[3]);
  hp[1] = make_float4(hv[4], hv[5], hv[6], hv[7]);
  xx[p] = ss;
}

// ---------------- K2: kNN top-16 (k=16, and k=12 is a prefix) ----------------
__global__ __launch_bounds__(64) void k_knn(const float* __restrict__ h,
                                            const float* __restrict__ xx,
                                            int* __restrict__ knn_idx) {
  __shared__ float dist[NN];
  int p = blockIdx.x;
  int b = p >> 11;
  int n = p & (NN - 1);
  int lane = threadIdx.x;
  const float* hb = h + (size_t)b * NN * 8;
  const float4* qp = (const float4*)(hb + (size_t)n * 8);
  float4 q0 = qp[0], q1 = qp[1];
  float xq = xx[p];
  const float* xxb = xx + (size_t)b * NN;
  for (int m = lane; m < NN; m += 64) {
    const float4* ap = (const float4*)(hb + (size_t)m * 8);
    float4 a0 = ap[0], a1 = ap[1];
    float inner = q0.x * a0.x + q0.y * a0.y + q0.z * a0.z + q0.w * a0.w +
                  q1.x * a1.x + q1.y * a1.y + q1.z * a1.z + q1.w * a1.w;
    dist[m] = 2.f * inner - xq - xxb[m];
  }
  __syncthreads();
  for (int r = 0; r < 16; ++r) {
    float best = -INFINITY;
    int bi = NN;
    for (int m = lane; m < NN; m += 64) {
      float v = dist[m];
      if (v > best) { best = v; bi = m; }
    }
#pragma unroll
    for (int s = 32; s >= 1; s >>= 1) {
      float ov = __shfl_xor(best, s);
      int oi = __shfl_xor(bi, s);
      if (ov > best || (ov == best && oi < bi)) { best = ov; bi = oi; }
    }
    if (lane == 0) {
      knn_idx[(size_t)p * 16 + r] = bi;
      dist[bi] = -INFINITY;
    }
    __syncthreads();
  }
}

// ---------------- weight pack: fp32 (O,C) -> bf16 MFMA B-fragment order ----------------
// dst[(kt*NCT + ct)*64 + lane][i] = w[col][k], col = ct*16+(lane&15), k = kt*32+(lane>>4)*8+i
__global__ __launch_bounds__(64) void k_pack(const float* __restrict__ src,
                                             short* __restrict__ dst,
                                             int O, int C) {
  int NCT = O >> 4;
  int blk = blockIdx.x;
  int ct = blk % NCT;
  int kt = blk / NCT;
  int l = threadIdx.x;
  int col = ct * 16 + (l & 15);
  bf16x8 v;
#pragma unroll
  for (int i = 0; i < 8; ++i) {
    int k = kt * 32 + ((l >> 4) << 3) + i;
    v[i] = (k < C) ? f2bf(src[(size_t)col * C + k]) : (short)0;
  }
  ((bf16x8*)dst)[(size_t)blk * 64 + l] = v;
}

// ---------------- K3: fused edge->conv1->conv2->att-score->pool->att-conv (MFMA) ----------------
// TILE=4 points/block, K padded to 16 rows/point => R=64 rows. 256 thr = 4 waves.
template <int KR, int FOFF>
__global__ __launch_bounds__(256, 4) void k_branch(
    const float* __restrict__ h, const int* __restrict__ knn_idx,
    const short* __restrict__ w1f, const float* __restrict__ s1, const float* __restrict__ b1,
    const short* __restrict__ w2f, const float* __restrict__ s2, const float* __restrict__ b2,
    const short* __restrict__ wattf,
    const short* __restrict__ wpf, const float* __restrict__ sp, const float* __restrict__ bp,
    short* __restrict__ fout) {
  __shared__ short e_s[64][48];    // edge feats, cols 0-15 real, 16-31 zero (K-pad), stride 96B
  __shared__ short g1_s[64][72];   // conv1 out 64ch, stride 144B (bank-balanced, 16B aligned)
  __shared__ short g2_s[64][136];  // conv2 out 128ch, stride 272B
  __shared__ short pool_s[16][136];

  int tid = threadIdx.x;
  int lane = tid & 63;
  int w = tid >> 6;
  int lr = lane & 15;
  int lg = lane >> 4;
  int pbase = blockIdx.x * 4;
  const float* hb = h + ((size_t)(pbase & ~(NN - 1))) * 8;

  // Phase A: edge features e = [nbr-ctr, ctr], bf16, zero K-pad + zero rows j>=KR
  if (tid < 64) {
    int t = tid >> 4, j = tid & 15;
    int p = pbase + t;
    const float* cp = h + (size_t)p * 8;
    bool real = (j < KR);
    int id = real ? knn_idx[(size_t)p * 16 + j] : 0;
    const float* np_ = hb + (size_t)id * 8;
#pragma unroll
    for (int c = 0; c < 8; ++c) {
      float cv = cp[c], nv = np_[c];
      e_s[tid][c] = real ? f2bf(nv - cv) : (short)0;
      e_s[tid][8 + c] = real ? f2bf(cv) : (short)0;
      e_s[tid][16 + c] = 0;
      e_s[tid][24 + c] = 0;
    }
  }
  __syncthreads();

  // Phase B: conv1 16->64 (K padded to 32, one MFMA per tile). wave w owns col-tile w.
  {
    int ct = w;
    int o = ct * 16 + lr;
    bf16x8 bfrag = ((const bf16x8*)w1f)[ct * 64 + lane];
    float scl = s1[o], bia = b1[o];
#pragma unroll
    for (int rt = 0; rt < 4; ++rt) {
      bf16x8 af = *(const bf16x8*)&e_s[rt * 16 + lr][lg * 8];
      f32x4 acc = {0.f, 0.f, 0.f, 0.f};
      acc = MFMA(af, bfrag, acc);
#pragma unroll
      for (int q = 0; q < 4; ++q) {
        int r = rt * 16 + lg * 4 + q;
        g1_s[r][o] = f2bf(fmaxf(acc[q] * scl + bia, 0.f));
      }
    }
  }
  __syncthreads();

  // Phase C: conv2 64->128, wave w owns col-tiles 2w, 2w+1
#pragma unroll
  for (int cti = 0; cti < 2; ++cti) {
    int ct = w * 2 + cti;
    int o = ct * 16 + lr;
    bf16x8 bf0 = ((const bf16x8*)w2f)[(0 * 8 + ct) * 64 + lane];
    bf16x8 bf1 = ((const bf16x8*)w2f)[(1 * 8 + ct) * 64 + lane];
    float scl = s2[o], bia = b2[o];
#pragma unroll
    for (int rt = 0; rt < 4; ++rt) {
      bf16x8 a0 = *(const bf16x8*)&g1_s[rt * 16 + lr][lg * 8];
      bf16x8 a1 = *(const bf16x8*)&g1_s[rt * 16 + lr][32 + lg * 8];
      f32x4 acc = {0.f, 0.f, 0.f, 0.f};
      acc = MFMA(a0, bf0, acc);
      acc = MFMA(a1, bf1, acc);
#pragma unroll
      for (int q = 0; q < 4; ++q) {
        int r = rt * 16 + lg * 4 + q;
        g2_s[r][o] = f2bf(fmaxf(acc[q] * scl + bia, 0.f));
      }
    }
  }
  __syncthreads();

  // Phase D: att score (sigmoid) * g2, sum over k rows -> pool_s. One row-tile == one point.
#pragma unroll
  for (int cti = 0; cti < 2; ++cti) {
    int ct = w * 2 + cti;
    int o = ct * 16 + lr;
    bf16x8 bfr[4];
#pragma unroll
    for (int kt = 0; kt < 4; ++kt) bfr[kt] = ((const bf16x8*)wattf)[(kt * 8 + ct) * 64 + lane];
#pragma unroll
    for (int rt = 0; rt < 4; ++rt) {
      f32x4 acc = {0.f, 0.f, 0.f, 0.f};
#pragma unroll
      for (int kt = 0; kt < 4; ++kt) {
        bf16x8 a = *(const bf16x8*)&g2_s[rt * 16 + lr][kt * 32 + lg * 8];
        acc = MFMA(a, bfr[kt], acc);
      }
      float v = 0.f;
#pragma unroll
      for (int q = 0; q < 4; ++q) {
        int jj = lg * 4 + q;
        float sg = 1.f / (1.f + __expf(-acc[q]));
        float g2v = bf2f(g2_s[rt * 16 + jj][o]);
        if (jj < KR) v += g2v * sg;   // mask padded rows (branch2)
      }
      v += __shfl_xor(v, 16);
      v += __shfl_xor(v, 32);
      if (lane < 16) pool_s[rt][o] = f2bf(v);
    }
  }
  __syncthreads();

  // Phase F: att conv 128->256 + bn + relu -> fbuf (bf16). Rows 4-15 of pool garbage/unused.
  {
    bf16x8 afr[4];
#pragma unroll
    for (int kt = 0; kt < 4; ++kt) afr[kt] = *(const bf16x8*)&pool_s[lr][kt * 32 + lg * 8];
#pragma unroll
    for (int cti = 0; cti < 4; ++cti) {
      int ct = w * 4 + cti;
      int o = ct * 16 + lr;
      f32x4 acc = {0.f, 0.f, 0.f, 0.f};
#pragma unroll
      for (int kt = 0; kt < 4; ++kt) {
        bf16x8 b = ((const bf16x8*)wpf)[(kt * 16 + ct) * 64 + lane];
        acc = MFMA(afr[kt], b, acc);
      }
      float scl = sp[o], bia = bp[o];
      if (lane < 16) {  // rows 0-3 = the 4 valid points (lg==0)
#pragma unroll
        for (int q = 0; q < 4; ++q) {
          float v = fmaxf(acc[q] * scl + bia, 0.f);
          fout[(size_t)(pbase + q) * 512 + FOFF + o] = f2bf(v);
        }
      }
    }
  }
}

// ---------------- K4: out = relu(bn(f @ wf^T)) computed transposed: M=channels, N=points ----------------
// Block: 64 out-channels (4 waves x 16) x 256 points. A = wf (packed frags), B = f staged in LDS.
__global__ __launch_bounds__(256, 4) void k_final(
    const short* __restrict__ fbuf, const short* __restrict__ wff,
    const float* __restrict__ sf, const float* __restrict__ bfv,
    float* __restrict__ out) {
  __shared__ short b_s[256][72];   // 256 points x 64 k-chunk, stride 144B
  int tid = threadIdx.x;
  int lane = tid & 63;
  int w = tid >> 6;
  int lr = lane & 15;
  int lg = lane >> 4;
  int ob = blockIdx.x;             // o tile: o = (ob*4+w)*16 + ...
  int p0 = blockIdx.y * 256;
  int rtg = ob * 4 + w;            // global 16-row A tile index (0..31)

  f32x4 acc[16];
#pragma unroll
  for (int ct = 0; ct < 16; ++ct) acc[ct] = (f32x4){0.f, 0.f, 0.f, 0.f};

  for (int kc = 0; kc < 512; kc += 64) {
    __syncthreads();
    // stage B: 256 rows x 64 k (bf16) = 32KB, coalesced 16B/thread chunks
#pragma unroll
    for (int c = 0; c < 8; ++c) {
      int idx = c * 256 + tid;
      int row = idx >> 3, seg = idx & 7;
      *(float4*)&b_s[row][seg * 8] =
          *(const float4*)(fbuf + ((size_t)(p0 + row) * 512 + kc + seg * 8));
    }
    __syncthreads();
    int kt = kc >> 5;
    bf16x8 a0 = ((const bf16x8*)wff)[((size_t)(kt + 0) * 32 + rtg) * 64 + lane];
    bf16x8 a1 = ((const bf16x8*)wff)[((size_t)(kt + 1) * 32 + rtg) * 64 + lane];
#pragma unroll
    for (int ct = 0; ct < 16; ++ct) {
      bf16x8 bb0 = *(const bf16x8*)&b_s[ct * 16 + lr][lg * 8];
      bf16x8 bb1 = *(const bf16x8*)&b_s[ct * 16 + lr][32 + lg * 8];
      acc[ct] = MFMA(a0, bb0, acc[ct]);
      acc[ct] = MFMA(a1, bb1, acc[ct]);
    }
  }

  int b = p0 >> 11;
  int nb = p0 & (NN - 1);
#pragma unroll
  for (int q = 0; q < 4; ++q) {
    int o = rtg * 16 + lg * 4 + q;
    float scl = sf[o], bia = bfv[o];
#pragma unroll
    for (int ct = 0; ct < 16; ++ct) {
      int n = nb + ct * 16 + lr;   // lanes lr=0..15 -> consecutive n: coalesced
      float v = fmaxf(acc[ct][q] * scl + bia, 0.f);
      out[((size_t)b * 512 + o) * NN + n] = v;
    }
  }
}

extern "C" void kernel_launch(void* const* d_in, const int* in_sizes, int n_in,
                              void* d_out, int out_size, void* d_ws, size_t ws_size,
                              hipStream_t stream) {
  const float* x      = (const float*)d_in[0];
  const float* lw     = (const float*)d_in[1];
  const float* ls     = (const float*)d_in[2];
  const float* lb     = (const float*)d_in[3];
  const float* w1     = (const float*)d_in[4];
  const float* s1     = (const float*)d_in[5];
  const float* b1     = (const float*)d_in[6];
  const float* w2     = (const float*)d_in[7];
  const float* s2     = (const float*)d_in[8];
  const float* b2     = (const float*)d_in[9];
  const float* w3     = (const float*)d_in[10];
  const float* s3     = (const float*)d_in[11];
  const float* b3     = (const float*)d_in[12];
  const float* w4     = (const float*)d_in[13];
  const float* s4     = (const float*)d_in[14];
  const float* b4     = (const float*)d_in[15];
  const float* a1_att = (const float*)d_in[16];
  const float* a1_w   = (const float*)d_in[17];
  const float* a1_s   = (const float*)d_in[18];
  const float* a1_b   = (const float*)d_in[19];
  const float* a2_att = (const float*)d_in[20];
  const float* a2_w   = (const float*)d_in[21];
  const float* a2_s   = (const float*)d_in[22];
  const float* a2_b   = (const float*)d_in[23];
  const float* wf     = (const float*)d_in[24];
  const float* sf     = (const float*)d_in[25];
  const float* bf     = (const float*)d_in[26];
  float* out = (float*)d_out;

  char* ws = (char*)d_ws;
  float* h   = (float*)ws;                          ws += (size_t)BB * NN * 8 * 4;
  float* xx  = (float*)ws;                          ws += (size_t)BB * NN * 4;
  int* knn_idx = (int*)ws;                          ws += (size_t)BB * NN * 16 * 4;
  short* fbuf  = (short*)ws;                        ws += (size_t)BB * NN * 512 * 2;
  short* w1f   = (short*)ws;                        ws += 1 * 4 * 64 * 8 * 2;
  short* w3f   = (short*)ws;                        ws += 1 * 4 * 64 * 8 * 2;
  short* w2f   = (short*)ws;                        ws += 2 * 8 * 64 * 8 * 2;
  short* w4f   = (short*)ws;                        ws += 2 * 8 * 64 * 8 * 2;
  short* wa1f  = (short*)ws;                        ws += 4 * 8 * 64 * 8 * 2;
  short* wa2f  = (short*)ws;                        ws += 4 * 8 * 64 * 8 * 2;
  short* wp1f  = (short*)ws;                        ws += 4 * 16 * 64 * 8 * 2;
  short* wp2f  = (short*)ws;                        ws += 4 * 16 * 64 * 8 * 2;
  short* wff   = (short*)ws;                        ws += 16 * 32 * 64 * 8 * 2;

  // pack weights (bf16 fragment layouts)
  k_pack<<<dim3(4),   dim3(64), 0, stream>>>(w1,     w1f, 64, 16);
  k_pack<<<dim3(4),   dim3(64), 0, stream>>>(w3,     w3f, 64, 16);
  k_pack<<<dim3(16),  dim3(64), 0, stream>>>(w2,     w2f, 128, 64);
  k_pack<<<dim3(16),  dim3(64), 0, stream>>>(w4,     w4f, 128, 64);
  k_pack<<<dim3(32),  dim3(64), 0, stream>>>(a1_att, wa1f, 128, 128);
  k_pack<<<dim3(32),  dim3(64), 0, stream>>>(a2_att, wa2f, 128, 128);
  k_pack<<<dim3(64),  dim3(64), 0, stream>>>(a1_w,   wp1f, 256, 128);
  k_pack<<<dim3(64),  dim3(64), 0, stream>>>(a2_w,   wp2f, 256, 128);
  k_pack<<<dim3(512), dim3(64), 0, stream>>>(wf,     wff, 512, 512);

  k_h<<<dim3((BB * NN + 255) / 256), dim3(256), 0, stream>>>(x, lw, ls, lb, h, xx);
  k_knn<<<dim3(BB * NN), dim3(64), 0, stream>>>(h, xx, knn_idx);
  k_branch<16, 0><<<dim3(BB * NN / 4), dim3(256), 0, stream>>>(
      h, knn_idx, w1f, s1, b1, w2f, s2, b2, wa1f, wp1f, a1_s, a1_b, fbuf);
  k_branch<12, 256><<<dim3(BB * NN / 4), dim3(256), 0, stream>>>(
      h, knn_idx, w3f, s3, b3, w4f, s4, b4, wa2f, wp2f, a2_s, a2_b, fbuf);
  k_final<<<dim3(8, 128), dim3(256), 0, stream>>>(fbuf, wff, sf, bf, out);
}

// Round 3
// 508.447 us; speedup vs baseline: 4.3610x; 1.0498x over previous
//
#include <hip/hip_runtime.h>
#include <hip/hip_bf16.h>
#include <math.h>

#define BB 16
#define NN 2048

typedef short bf16x8 __attribute__((ext_vector_type(8)));
typedef float f32x4 __attribute__((ext_vector_type(4)));

#define MFMA(a, b, c) __builtin_amdgcn_mfma_f32_16x16x32_bf16(a, b, c, 0, 0, 0)

static __device__ __forceinline__ short f2bf(float f) {
  union { float f; unsigned u; } v; v.f = f;
  unsigned r = v.u + 0x7fffu + ((v.u >> 16) & 1u);
  return (short)(r >> 16);
}
static __device__ __forceinline__ float bf2f(short s) {
  union { unsigned u; float f; } v; v.u = ((unsigned)(unsigned short)s) << 16;
  return v.f;
}

// ---------------- K1: h = relu(bn(conv1d(x))) ; xx = ||h||^2 ----------------
__global__ __launch_bounds__(256) void k_h(const float* __restrict__ x,
                                           const float* __restrict__ lw,
                                           const float* __restrict__ ls,
                                           const float* __restrict__ lb,
                                           float* __restrict__ h,
                                           float* __restrict__ xx) {
  int p = blockIdx.x * blockDim.x + threadIdx.x;
  if (p >= BB * NN) return;
  int b = p >> 11;
  int n = p & (NN - 1);
  const float* xb = x + (size_t)b * 3 * NN + n;
  float x0 = xb[0], x1 = xb[NN], x2 = xb[2 * NN];
  float hv[8];
  float ss = 0.f;
#pragma unroll
  for (int o = 0; o < 8; ++o) {
    float v = x0 * lw[o * 3 + 0] + x1 * lw[o * 3 + 1] + x2 * lw[o * 3 + 2];
    v = fmaxf(v * ls[o] + lb[o], 0.f);
    hv[o] = v;
    ss += v * v;  // same order as k_knn inner product -> self-dist exactly 0
  }
  float4* hp = (float4*)(h + (size_t)p * 8);
  hp[0] = make_float4(hv[0], hv[1], hv[2], hv[3]);
  hp[1] = make_float4(hv[4], hv[5], hv[6], hv[7]);
  xx[p] = ss;
}

// ---------------- K2: kNN top-16 via radix-threshold + 64-lane bitonic ----------------
__global__ __launch_bounds__(64) void k_knn(const float* __restrict__ h,
                                            const float* __restrict__ xx,
                                            int* __restrict__ knn_idx) {
  __shared__ float dist[NN];       // 8 KB
  __shared__ unsigned hist[256];   // 1 KB
  __shared__ float cand_v[64];
  __shared__ int cand_i[64];
  __shared__ unsigned cnt_s;
  __shared__ unsigned B_s;

  int p = blockIdx.x;
  int b = p >> 11;
  int n = p & (NN - 1);
  int lane = threadIdx.x;
  const float* hb = h + (size_t)b * NN * 8;
  const float4* qp = (const float4*)(hb + (size_t)n * 8);
  float4 q0 = qp[0], q1 = qp[1];
  float xq = xx[p];
  const float* xxb = xx + (size_t)b * NN;

  hist[lane] = 0; hist[lane + 64] = 0; hist[lane + 128] = 0; hist[lane + 192] = 0;
  if (lane == 0) cnt_s = 0;
  __syncthreads();

  // distances + monotone keys + histogram of top 8 key bits
  unsigned kv[32];
#pragma unroll
  for (int i = 0; i < 32; ++i) {
    int m = lane + (i << 6);
    const float4* ap = (const float4*)(hb + (size_t)m * 8);
    float4 a0 = ap[0], a1 = ap[1];
    float inner = q0.x * a0.x + q0.y * a0.y + q0.z * a0.z + q0.w * a0.w +
                  q1.x * a1.x + q1.y * a1.y + q1.z * a1.z + q1.w * a1.w;
    float d = 2.f * inner - xq - xxb[m];
    dist[m] = d;
    unsigned u = __float_as_uint(d);
    unsigned key = ((int)u >= 0) ? (u | 0x80000000u) : ~u;  // larger float => larger key
    kv[i] = key;
    atomicAdd(&hist[key >> 24], 1u);
  }
  __syncthreads();

  // find boundary bin B = largest bin with suffix-count >= 16
  uint4 h4 = *(const uint4*)&hist[lane * 4];
  unsigned s = h4.x + h4.y + h4.z + h4.w;
  unsigned suf = s;
#pragma unroll
  for (int d = 1; d < 64; d <<= 1) {
    unsigned t = __shfl_down(suf, d);
    suf += (lane + d < 64) ? t : 0u;
  }
  unsigned above = suf - s;  // count in bins >= 4*(lane+1)
  if (suf >= 16u && above < 16u) {
    unsigned c = above, B;
    c += h4.w;
    if (c >= 16u) B = lane * 4 + 3;
    else { c += h4.z;
      if (c >= 16u) B = lane * 4 + 2;
      else { c += h4.y;
        if (c >= 16u) B = lane * 4 + 1;
        else B = lane * 4; } }
    B_s = B;
  }
  __syncthreads();
  unsigned Bkey = B_s << 24;

  // gather candidates (expected ~23, capacity 64)
#pragma unroll
  for (int i = 0; i < 32; ++i) {
    if (kv[i] >= Bkey) {
      unsigned pos = atomicAdd(&cnt_s, 1u);
      if (pos < 64u) {
        int m = lane + (i << 6);
        cand_v[pos] = dist[m];
        cand_i[pos] = m;
      }
    }
  }
  __syncthreads();
  unsigned C = cnt_s;

  if (C <= 64u) {
    float v = (lane < (int)C) ? cand_v[lane] : -INFINITY;
    int id = (lane < (int)C) ? cand_i[lane] : 0x7FFFFFFF;
    // bitonic sort across 64 lanes: descending value, ascending index on ties
#pragma unroll
    for (int k = 2; k <= 64; k <<= 1) {
#pragma unroll
      for (int j = k >> 1; j >= 1; j >>= 1) {
        float ov = __shfl_xor(v, j);
        int oi = __shfl_xor(id, j);
        bool lower = ((lane & j) == 0);
        bool dirAsc = ((lane & k) == 0);
        bool mineFirst = (v > ov) || (v == ov && id < oi);
        bool keepMine = (dirAsc == lower) ? mineFirst : !mineFirst;
        if (!keepMine) { v = ov; id = oi; }
      }
    }
    if (lane < 16) knn_idx[(size_t)p * 16 + lane] = id;
  } else {
    // exact fallback (boundary bin overflow): original 16-round argmax
    for (int r = 0; r < 16; ++r) {
      float best = -INFINITY;
      int bi = NN;
      for (int m = lane; m < NN; m += 64) {
        float v = dist[m];
        if (v > best) { best = v; bi = m; }
      }
#pragma unroll
      for (int s2 = 32; s2 >= 1; s2 >>= 1) {
        float ov = __shfl_xor(best, s2);
        int oi = __shfl_xor(bi, s2);
        if (ov > best || (ov == best && oi < bi)) { best = ov; bi = oi; }
      }
      if (lane == 0) {
        knn_idx[(size_t)p * 16 + r] = bi;
        dist[bi] = -INFINITY;
      }
      __syncthreads();
    }
  }
}

// ---------------- weight pack: fp32 (O,C) -> bf16 MFMA B-fragment order ----------------
// dst[(kt*NCT + ct)*64 + lane][i] = w[col][k], col = ct*16+(lane&15), k = kt*32+(lane>>4)*8+i
__global__ __launch_bounds__(64) void k_pack(const float* __restrict__ src,
                                             short* __restrict__ dst,
                                             int O, int C) {
  int NCT = O >> 4;
  int blk = blockIdx.x;
  int ct = blk % NCT;
  int kt = blk / NCT;
  int l = threadIdx.x;
  int col = ct * 16 + (l & 15);
  bf16x8 v;
#pragma unroll
  for (int i = 0; i < 8; ++i) {
    int k = kt * 32 + ((l >> 4) << 3) + i;
    v[i] = (k < C) ? f2bf(src[(size_t)col * C + k]) : (short)0;
  }
  ((bf16x8*)dst)[(size_t)blk * 64 + l] = v;
}

// ---------------- K3: fused edge->conv1->conv2->att-score->pool->att-conv (MFMA) ----------------
// TILE=4 points/block, K padded to 16 rows/point => R=64 rows. 256 thr = 4 waves.
template <int KR, int FOFF>
__global__ __launch_bounds__(256, 4) void k_branch(
    const float* __restrict__ h, const int* __restrict__ knn_idx,
    const short* __restrict__ w1f, const float* __restrict__ s1, const float* __restrict__ b1,
    const short* __restrict__ w2f, const float* __restrict__ s2, const float* __restrict__ b2,
    const short* __restrict__ wattf,
    const short* __restrict__ wpf, const float* __restrict__ sp, const float* __restrict__ bp,
    short* __restrict__ fout) {
  __shared__ short e_s[64][48];    // edge feats, cols 0-15 real, 16-31 zero (K-pad)
  __shared__ short g1_s[64][72];   // conv1 out 64ch, stride 144B
  __shared__ short g2_s[64][136];  // conv2 out 128ch, stride 272B
  __shared__ short pool_s[16][136];

  int tid = threadIdx.x;
  int lane = tid & 63;
  int w = tid >> 6;
  int lr = lane & 15;
  int lg = lane >> 4;
  int pbase = blockIdx.x * 4;
  const float* hb = h + ((size_t)(pbase & ~(NN - 1))) * 8;

  // Phase A: edge features e = [nbr-ctr, ctr], bf16, zero K-pad + zero rows j>=KR
  if (tid < 64) {
    int t = tid >> 4, j = tid & 15;
    int p = pbase + t;
    const float* cp = h + (size_t)p * 8;
    bool real = (j < KR);
    int id = real ? knn_idx[(size_t)p * 16 + j] : 0;
    const float* np_ = hb + (size_t)id * 8;
#pragma unroll
    for (int c = 0; c < 8; ++c) {
      float cv = cp[c], nv = np_[c];
      e_s[tid][c] = real ? f2bf(nv - cv) : (short)0;
      e_s[tid][8 + c] = real ? f2bf(cv) : (short)0;
      e_s[tid][16 + c] = 0;
      e_s[tid][24 + c] = 0;
    }
  }
  __syncthreads();

  // Phase B: conv1 16->64
  {
    int ct = w;
    int o = ct * 16 + lr;
    bf16x8 bfrag = ((const bf16x8*)w1f)[ct * 64 + lane];
    float scl = s1[o], bia = b1[o];
#pragma unroll
    for (int rt = 0; rt < 4; ++rt) {
      bf16x8 af = *(const bf16x8*)&e_s[rt * 16 + lr][lg * 8];
      f32x4 acc = {0.f, 0.f, 0.f, 0.f};
      acc = MFMA(af, bfrag, acc);
#pragma unroll
      for (int q = 0; q < 4; ++q) {
        int r = rt * 16 + lg * 4 + q;
        g1_s[r][o] = f2bf(fmaxf(acc[q] * scl + bia, 0.f));
      }
    }
  }
  __syncthreads();

  // Phase C: conv2 64->128
#pragma unroll
  for (int cti = 0; cti < 2; ++cti) {
    int ct = w * 2 + cti;
    int o = ct * 16 + lr;
    bf16x8 bf0 = ((const bf16x8*)w2f)[(0 * 8 + ct) * 64 + lane];
    bf16x8 bf1 = ((const bf16x8*)w2f)[(1 * 8 + ct) * 64 + lane];
    float scl = s2[o], bia = b2[o];
#pragma unroll
    for (int rt = 0; rt < 4; ++rt) {
      bf16x8 a0 = *(const bf16x8*)&g1_s[rt * 16 + lr][lg * 8];
      bf16x8 a1 = *(const bf16x8*)&g1_s[rt * 16 + lr][32 + lg * 8];
      f32x4 acc = {0.f, 0.f, 0.f, 0.f};
      acc = MFMA(a0, bf0, acc);
      acc = MFMA(a1, bf1, acc);
#pragma unroll
      for (int q = 0; q < 4; ++q) {
        int r = rt * 16 + lg * 4 + q;
        g2_s[r][o] = f2bf(fmaxf(acc[q] * scl + bia, 0.f));
      }
    }
  }
  __syncthreads();

  // Phase D: att score (sigmoid) * g2, sum over k rows -> pool_s
#pragma unroll
  for (int cti = 0; cti < 2; ++cti) {
    int ct = w * 2 + cti;
    int o = ct * 16 + lr;
    bf16x8 bfr[4];
#pragma unroll
    for (int kt = 0; kt < 4; ++kt) bfr[kt] = ((const bf16x8*)wattf)[(kt * 8 + ct) * 64 + lane];
#pragma unroll
    for (int rt = 0; rt < 4; ++rt) {
      f32x4 acc = {0.f, 0.f, 0.f, 0.f};
#pragma unroll
      for (int kt = 0; kt < 4; ++kt) {
        bf16x8 a = *(const bf16x8*)&g2_s[rt * 16 + lr][kt * 32 + lg * 8];
        acc = MFMA(a, bfr[kt], acc);
      }
      float v = 0.f;
#pragma unroll
      for (int q = 0; q < 4; ++q) {
        int jj = lg * 4 + q;
        float sg = 1.f / (1.f + __expf(-acc[q]));
        float g2v = bf2f(g2_s[rt * 16 + jj][o]);
        if (jj < KR) v += g2v * sg;   // mask padded rows (branch2)
      }
      v += __shfl_xor(v, 16);
      v += __shfl_xor(v, 32);
      if (lane < 16) pool_s[rt][o] = f2bf(v);
    }
  }
  __syncthreads();

  // Phase F: att conv 128->256 + bn + relu -> fbuf (bf16)
  {
    bf16x8 afr[4];
#pragma unroll
    for (int kt = 0; kt < 4; ++kt) afr[kt] = *(const bf16x8*)&pool_s[lr][kt * 32 + lg * 8];
#pragma unroll
    for (int cti = 0; cti < 4; ++cti) {
      int ct = w * 4 + cti;
      int o = ct * 16 + lr;
      f32x4 acc = {0.f, 0.f, 0.f, 0.f};
#pragma unroll
      for (int kt = 0; kt < 4; ++kt) {
        bf16x8 b = ((const bf16x8*)wpf)[(kt * 16 + ct) * 64 + lane];
        acc = MFMA(afr[kt], b, acc);
      }
      float scl = sp[o], bia = bp[o];
      if (lane < 16) {
#pragma unroll
        for (int q = 0; q < 4; ++q) {
          float v = fmaxf(acc[q] * scl + bia, 0.f);
          fout[(size_t)(pbase + q) * 512 + FOFF + o] = f2bf(v);
        }
      }
    }
  }
}

// ---------------- K4: out = relu(bn(f @ wf^T)) computed transposed ----------------
__global__ __launch_bounds__(256, 4) void k_final(
    const short* __restrict__ fbuf, const short* __restrict__ wff,
    const float* __restrict__ sf, const float* __restrict__ bfv,
    float* __restrict__ out) {
  __shared__ short b_s[256][72];
  int tid = threadIdx.x;
  int lane = tid & 63;
  int w = tid >> 6;
  int lr = lane & 15;
  int lg = lane >> 4;
  int ob = blockIdx.x;
  int p0 = blockIdx.y * 256;
  int rtg = ob * 4 + w;

  f32x4 acc[16];
#pragma unroll
  for (int ct = 0; ct < 16; ++ct) acc[ct] = (f32x4){0.f, 0.f, 0.f, 0.f};

  for (int kc = 0; kc < 512; kc += 64) {
    __syncthreads();
#pragma unroll
    for (int c = 0; c < 8; ++c) {
      int idx = c * 256 + tid;
      int row = idx >> 3, seg = idx & 7;
      *(float4*)&b_s[row][seg * 8] =
          *(const float4*)(fbuf + ((size_t)(p0 + row) * 512 + kc + seg * 8));
    }
    __syncthreads();
    int kt = kc >> 5;
    bf16x8 a0 = ((const bf16x8*)wff)[((size_t)(kt + 0) * 32 + rtg) * 64 + lane];
    bf16x8 a1 = ((const bf16x8*)wff)[((size_t)(kt + 1) * 32 + rtg) * 64 + lane];
#pragma unroll
    for (int ct = 0; ct < 16; ++ct) {
      bf16x8 bb0 = *(const bf16x8*)&b_s[ct * 16 + lr][lg * 8];
      bf16x8 bb1 = *(const bf16x8*)&b_s[ct * 16 + lr][32 + lg * 8];
      acc[ct] = MFMA(a0, bb0, acc[ct]);
      acc[ct] = MFMA(a1, bb1, acc[ct]);
    }
  }

  int b = p0 >> 11;
  int nb = p0 & (NN - 1);
#pragma unroll
  for (int q = 0; q < 4; ++q) {
    int o = rtg * 16 + lg * 4 + q;
    float scl = sf[o], bia = bfv[o];
#pragma unroll
    for (int ct = 0; ct < 16; ++ct) {
      int n = nb + ct * 16 + lr;
      float v = fmaxf(acc[ct][q] * scl + bia, 0.f);
      out[((size_t)b * 512 + o) * NN + n] = v;
    }
  }
}

extern "C" void kernel_launch(void* const* d_in, const int* in_sizes, int n_in,
                              void* d_out, int out_size, void* d_ws, size_t ws_size,
                              hipStream_t stream) {
  const float* x      = (const float*)d_in[0];
  const float* lw     = (const float*)d_in[1];
  const float* ls     = (const float*)d_in[2];
  const float* lb     = (const float*)d_in[3];
  const float* w1     = (const float*)d_in[4];
  const float* s1     = (const float*)d_in[5];
  const float* b1     = (const float*)d_in[6];
  const float* w2     = (const float*)d_in[7];
  const float* s2     = (const float*)d_in[8];
  const float* b2     = (const float*)d_in[9];
  const float* w3     = (const float*)d_in[10];
  const float* s3     = (const float*)d_in[11];
  const float* b3     = (const float*)d_in[12];
  const float* w4     = (const float*)d_in[13];
  const float* s4     = (const float*)d_in[14];
  const float* b4     = (const float*)d_in[15];
  const float* a1_att = (const float*)d_in[16];
  const float* a1_w   = (const float*)d_in[17];
  const float* a1_s   = (const float*)d_in[18];
  const float* a1_b   = (const float*)d_in[19];
  const float* a2_att = (const float*)d_in[20];
  const float* a2_w   = (const float*)d_in[21];
  const float* a2_s   = (const float*)d_in[22];
  const float* a2_b   = (const float*)d_in[23];
  const float* wf     = (const float*)d_in[24];
  const float* sf     = (const float*)d_in[25];
  const float* bf     = (const float*)d_in[26];
  float* out = (float*)d_out;

  char* ws = (char*)d_ws;
  float* h   = (float*)ws;                          ws += (size_t)BB * NN * 8 * 4;
  float* xx  = (float*)ws;                          ws += (size_t)BB * NN * 4;
  int* knn_idx = (int*)ws;                          ws += (size_t)BB * NN * 16 * 4;
  short* fbuf  = (short*)ws;                        ws += (size_t)BB * NN * 512 * 2;
  short* w1f   = (short*)ws;                        ws += 1 * 4 * 64 * 8 * 2;
  short* w3f   = (short*)ws;                        ws += 1 * 4 * 64 * 8 * 2;
  short* w2f   = (short*)ws;                        ws += 2 * 8 * 64 * 8 * 2;
  short* w4f   = (short*)ws;                        ws += 2 * 8 * 64 * 8 * 2;
  short* wa1f  = (short*)ws;                        ws += 4 * 8 * 64 * 8 * 2;
  short* wa2f  = (short*)ws;                        ws += 4 * 8 * 64 * 8 * 2;
  short* wp1f  = (short*)ws;                        ws += 4 * 16 * 64 * 8 * 2;
  short* wp2f  = (short*)ws;                        ws += 4 * 16 * 64 * 8 * 2;
  short* wff   = (short*)ws;                        ws += 16 * 32 * 64 * 8 * 2;

  k_pack<<<dim3(4),   dim3(64), 0, stream>>>(w1,     w1f, 64, 16);
  k_pack<<<dim3(4),   dim3(64), 0, stream>>>(w3,     w3f, 64, 16);
  k_pack<<<dim3(16),  dim3(64), 0, stream>>>(w2,     w2f, 128, 64);
  k_pack<<<dim3(16),  dim3(64), 0, stream>>>(w4,     w4f, 128, 64);
  k_pack<<<dim3(32),  dim3(64), 0, stream>>>(a1_att, wa1f, 128, 128);
  k_pack<<<dim3(32),  dim3(64), 0, stream>>>(a2_att, wa2f, 128, 128);
  k_pack<<<dim3(64),  dim3(64), 0, stream>>>(a1_w,   wp1f, 256, 128);
  k_pack<<<dim3(64),  dim3(64), 0, stream>>>(a2_w,   wp2f, 256, 128);
  k_pack<<<dim3(512), dim3(64), 0, stream>>>(wf,     wff, 512, 512);

  k_h<<<dim3((BB * NN + 255) / 256), dim3(256), 0, stream>>>(x, lw, ls, lb, h, xx);
  k_knn<<<dim3(BB * NN), dim3(64), 0, stream>>>(h, xx, knn_idx);
  k_branch<16, 0><<<dim3(BB * NN / 4), dim3(256), 0, stream>>>(
      h, knn_idx, w1f, s1, b1, w2f, s2, b2, wa1f, wp1f, a1_s, a1_b, fbuf);
  k_branch<12, 256><<<dim3(BB * NN / 4), dim3(256), 0, stream>>>(
      h, knn_idx, w3f, s3, b3, w4f, s4, b4, wa2f, wp2f, a2_s, a2_b, fbuf);
  k_final<<<dim3(8, 128), dim3(256), 0, stream>>>(fbuf, wff, sf, bf, out);
}

// Round 4
// 396.494 us; speedup vs baseline: 5.5923x; 1.2824x over previous
//
#include <hip/hip_runtime.h>
#include <hip/hip_bf16.h>
#include <math.h>

#define BB 16
#define NN 2048

typedef short bf16x8 __attribute__((ext_vector_type(8)));
typedef float f32x4 __attribute__((ext_vector_type(4)));

#define MFMA(a, b, c) __builtin_amdgcn_mfma_f32_16x16x32_bf16(a, b, c, 0, 0, 0)

static __device__ __forceinline__ short f2bf(float f) {
  union { float f; unsigned u; } v; v.f = f;
  unsigned r = v.u + 0x7fffu + ((v.u >> 16) & 1u);
  return (short)(r >> 16);
}
static __device__ __forceinline__ float bf2f(short s) {
  union { unsigned u; float f; } v; v.u = ((unsigned)(unsigned short)s) << 16;
  return v.f;
}

// ---------------- K1: h = relu(bn(conv1d(x))) ; xx = ||h||^2 ----------------
__global__ __launch_bounds__(256) void k_h(const float* __restrict__ x,
                                           const float* __restrict__ lw,
                                           const float* __restrict__ ls,
                                           const float* __restrict__ lb,
                                           float* __restrict__ h,
                                           float* __restrict__ xx) {
  int p = blockIdx.x * blockDim.x + threadIdx.x;
  if (p >= BB * NN) return;
  int b = p >> 11;
  int n = p & (NN - 1);
  const float* xb = x + (size_t)b * 3 * NN + n;
  float x0 = xb[0], x1 = xb[NN], x2 = xb[2 * NN];
  float hv[8];
  float ss = 0.f;
#pragma unroll
  for (int o = 0; o < 8; ++o) {
    float v = x0 * lw[o * 3 + 0] + x1 * lw[o * 3 + 1] + x2 * lw[o * 3 + 2];
    v = fmaxf(v * ls[o] + lb[o], 0.f);
    hv[o] = v;
    ss += v * v;  // same order as k_knn inner product -> self-dist exactly 0
  }
  float4* hp = (float4*)(h + (size_t)p * 8);
  hp[0] = make_float4(hv[0], hv[1], hv[2], hv[3]);
  hp[1] = make_float4(hv[4], hv[5], hv[6], hv[7]);
  xx[p] = ss;
}

// ---------------- K2: kNN top-16, one thread per (query, half), exact ----------------
// 512 blocks x 128 threads. Block handles 64 queries; thread tid<64 scans candidates
// [0,1024), tid>=64 scans [1024,2048) for query (tid&63). Per-thread sorted top-16 of
// packed u64 keys; candidates beating the 16th-best pushed to LDS stack; periodic
// bitonic merge. Halves merged at the end. Exact jax tie order (desc value, asc index).
__global__ __launch_bounds__(128, 1) void k_knn(const float* __restrict__ h,
                                                const float* __restrict__ xx,
                                                int* __restrict__ knn_idx) {
  __shared__ float hbuf[2][512][8];               // 32 KB candidate h chunk (per half)
  __shared__ float xbuf[2][512];                  // 4 KB
  __shared__ unsigned long long stk[128][17];     // 17-stride: 2-way bank pattern
  __shared__ unsigned long long mrg[64][17];

  int tid = threadIdx.x;
  int lane = tid & 63;
  int half = tid >> 6;
  int blk = blockIdx.x;
  int b = blk >> 5;                 // 32 blocks per batch
  int qloc = ((blk & 31) << 6) + lane;
  int p = (b << 11) + qloc;
  const float* hb = h + ((size_t)b << 11) * 8;
  const float* xxb = xx + ((size_t)b << 11);

  const float4* qp = (const float4*)(hb + (size_t)qloc * 8);
  float4 q0 = qp[0], q1 = qp[1];
  float xq = xxb[qloc];

  unsigned long long a[16];         // sorted ascending; a[0] = 16th best (threshold)
#pragma unroll
  for (int i = 0; i < 16; ++i) a[i] = 0ULL;  // real keys always > 0
  int cnt = 0;

  auto flush = [&]() {
    unsigned long long c[16];
#pragma unroll
    for (int j = 0; j < 16; ++j) c[j] = (j < cnt) ? stk[tid][j] : 0ULL;
    cnt = 0;
    // bitonic sort 16 ascending
#pragma unroll
    for (int k = 2; k <= 16; k <<= 1)
#pragma unroll
      for (int j = k >> 1; j > 0; j >>= 1)
#pragma unroll
        for (int i = 0; i < 16; ++i) {
          int l = i ^ j;
          if (l > i) {
            bool up = ((i & k) == 0);
            unsigned long long xi = c[i], xl = c[l];
            bool sw = up ? (xi > xl) : (xi < xl);
            if (sw) { c[i] = xl; c[l] = xi; }
          }
        }
    // merge-max of two sorted-16 -> bitonic -> clean ascending
    unsigned long long m[16];
#pragma unroll
    for (int i = 0; i < 16; ++i) {
      unsigned long long bi = c[15 - i];
      m[i] = (a[i] > bi) ? a[i] : bi;
    }
#pragma unroll
    for (int j = 8; j > 0; j >>= 1)
#pragma unroll
      for (int i = 0; i < 16; ++i) {
        int l = i ^ j;
        if (l > i && m[i] > m[l]) { unsigned long long t = m[i]; m[i] = m[l]; m[l] = t; }
      }
#pragma unroll
    for (int i = 0; i < 16; ++i) a[i] = m[i];
  };

  for (int ch = 0; ch < 2; ++ch) {
    __syncthreads();
    // stage both halves' 512-candidate chunks (cooperative, coalesced)
#pragma unroll
    for (int i = 0; i < 16; ++i) {
      int f = i * 128 + tid;            // 2048 float4s
      int buf = f >> 10, r = f & 1023;
      int cand = r >> 1, part = r & 1;
      *(float4*)&hbuf[buf][cand][part * 4] =
          *(const float4*)(hb + ((size_t)(buf * 1024 + ch * 512 + cand)) * 8 + part * 4);
    }
#pragma unroll
    for (int i = 0; i < 8; ++i) {
      int f = i * 128 + tid;            // 1024 floats
      int buf = f >> 9, cand = f & 511;
      xbuf[buf][cand] = xxb[buf * 1024 + ch * 512 + cand];
    }
    __syncthreads();

    int mbase = half * 1024 + ch * 512;
    for (int s4 = 0; s4 < 512; s4 += 4) {
#pragma unroll
      for (int u = 0; u < 4; ++u) {
        int s = s4 + u;
        int m = mbase + s;
        float4 a0 = *(const float4*)&hbuf[half][s][0];
        float4 a1 = *(const float4*)&hbuf[half][s][4];
        float xm = xbuf[half][s];
        float inner = q0.x * a0.x + q0.y * a0.y + q0.z * a0.z + q0.w * a0.w +
                      q1.x * a1.x + q1.y * a1.y + q1.z * a1.z + q1.w * a1.w;
        float d = 2.f * inner - xq - xm;
        unsigned uu = __float_as_uint(d);
        unsigned key = ((int)uu >= 0) ? (uu | 0x80000000u) : ~uu;
        unsigned long long key64 =
            ((unsigned long long)key << 32) | (unsigned)(NN - 1 - m);
        if (key64 > a[0]) {
          stk[tid][cnt] = key64;
          cnt++;
        }
      }
      if (__any(cnt >= 12)) flush();
    }
  }
  if (__any(cnt > 0)) flush();

  // cross-half merge
  if (half == 1) {
#pragma unroll
    for (int i = 0; i < 16; ++i) mrg[lane][i] = a[i];
  }
  __syncthreads();
  if (half == 0) {
    unsigned long long m[16];
#pragma unroll
    for (int i = 0; i < 16; ++i) {
      unsigned long long bi = mrg[lane][15 - i];
      m[i] = (a[i] > bi) ? a[i] : bi;
    }
#pragma unroll
    for (int j = 8; j > 0; j >>= 1)
#pragma unroll
      for (int i = 0; i < 16; ++i) {
        int l = i ^ j;
        if (l > i && m[i] > m[l]) { unsigned long long t = m[i]; m[i] = m[l]; m[l] = t; }
      }
    int ids[16];
#pragma unroll
    for (int r = 0; r < 16; ++r)
      ids[r] = (NN - 1) - (int)(unsigned)(m[15 - r] & 0xFFFFFFFFULL);
    int4* op = (int4*)(knn_idx + (size_t)p * 16);
    op[0] = make_int4(ids[0], ids[1], ids[2], ids[3]);
    op[1] = make_int4(ids[4], ids[5], ids[6], ids[7]);
    op[2] = make_int4(ids[8], ids[9], ids[10], ids[11]);
    op[3] = make_int4(ids[12], ids[13], ids[14], ids[15]);
  }
}

// ---------------- weight pack: fp32 (O,C) -> bf16 MFMA B-fragment order ----------------
__global__ __launch_bounds__(64) void k_pack(const float* __restrict__ src,
                                             short* __restrict__ dst,
                                             int O, int C) {
  int NCT = O >> 4;
  int blk = blockIdx.x;
  int ct = blk % NCT;
  int kt = blk / NCT;
  int l = threadIdx.x;
  int col = ct * 16 + (l & 15);
  bf16x8 v;
#pragma unroll
  for (int i = 0; i < 8; ++i) {
    int k = kt * 32 + ((l >> 4) << 3) + i;
    v[i] = (k < C) ? f2bf(src[(size_t)col * C + k]) : (short)0;
  }
  ((bf16x8*)dst)[(size_t)blk * 64 + l] = v;
}

// ---------------- K3: fused edge->conv1->conv2->att-score->pool->att-conv (MFMA) ----------------
template <int KR, int FOFF>
__global__ __launch_bounds__(256, 4) void k_branch(
    const float* __restrict__ h, const int* __restrict__ knn_idx,
    const short* __restrict__ w1f, const float* __restrict__ s1, const float* __restrict__ b1,
    const short* __restrict__ w2f, const float* __restrict__ s2, const float* __restrict__ b2,
    const short* __restrict__ wattf,
    const short* __restrict__ wpf, const float* __restrict__ sp, const float* __restrict__ bp,
    short* __restrict__ fout) {
  __shared__ short e_s[64][48];
  __shared__ short g1_s[64][72];
  __shared__ short g2_s[64][136];
  __shared__ short pool_s[16][136];

  int tid = threadIdx.x;
  int lane = tid & 63;
  int w = tid >> 6;
  int lr = lane & 15;
  int lg = lane >> 4;
  int pbase = blockIdx.x * 4;
  const float* hb = h + ((size_t)(pbase & ~(NN - 1))) * 8;

  if (tid < 64) {
    int t = tid >> 4, j = tid & 15;
    int p = pbase + t;
    const float* cp = h + (size_t)p * 8;
    bool real = (j < KR);
    int id = real ? knn_idx[(size_t)p * 16 + j] : 0;
    const float* np_ = hb + (size_t)id * 8;
#pragma unroll
    for (int c = 0; c < 8; ++c) {
      float cv = cp[c], nv = np_[c];
      e_s[tid][c] = real ? f2bf(nv - cv) : (short)0;
      e_s[tid][8 + c] = real ? f2bf(cv) : (short)0;
      e_s[tid][16 + c] = 0;
      e_s[tid][24 + c] = 0;
    }
  }
  __syncthreads();

  {
    int ct = w;
    int o = ct * 16 + lr;
    bf16x8 bfrag = ((const bf16x8*)w1f)[ct * 64 + lane];
    float scl = s1[o], bia = b1[o];
#pragma unroll
    for (int rt = 0; rt < 4; ++rt) {
      bf16x8 af = *(const bf16x8*)&e_s[rt * 16 + lr][lg * 8];
      f32x4 acc = {0.f, 0.f, 0.f, 0.f};
      acc = MFMA(af, bfrag, acc);
#pragma unroll
      for (int q = 0; q < 4; ++q) {
        int r = rt * 16 + lg * 4 + q;
        g1_s[r][o] = f2bf(fmaxf(acc[q] * scl + bia, 0.f));
      }
    }
  }
  __syncthreads();

#pragma unroll
  for (int cti = 0; cti < 2; ++cti) {
    int ct = w * 2 + cti;
    int o = ct * 16 + lr;
    bf16x8 bf0 = ((const bf16x8*)w2f)[(0 * 8 + ct) * 64 + lane];
    bf16x8 bf1 = ((const bf16x8*)w2f)[(1 * 8 + ct) * 64 + lane];
    float scl = s2[o], bia = b2[o];
#pragma unroll
    for (int rt = 0; rt < 4; ++rt) {
      bf16x8 a0 = *(const bf16x8*)&g1_s[rt * 16 + lr][lg * 8];
      bf16x8 a1 = *(const bf16x8*)&g1_s[rt * 16 + lr][32 + lg * 8];
      f32x4 acc = {0.f, 0.f, 0.f, 0.f};
      acc = MFMA(a0, bf0, acc);
      acc = MFMA(a1, bf1, acc);
#pragma unroll
      for (int q = 0; q < 4; ++q) {
        int r = rt * 16 + lg * 4 + q;
        g2_s[r][o] = f2bf(fmaxf(acc[q] * scl + bia, 0.f));
      }
    }
  }
  __syncthreads();

#pragma unroll
  for (int cti = 0; cti < 2; ++cti) {
    int ct = w * 2 + cti;
    int o = ct * 16 + lr;
    bf16x8 bfr[4];
#pragma unroll
    for (int kt = 0; kt < 4; ++kt) bfr[kt] = ((const bf16x8*)wattf)[(kt * 8 + ct) * 64 + lane];
#pragma unroll
    for (int rt = 0; rt < 4; ++rt) {
      f32x4 acc = {0.f, 0.f, 0.f, 0.f};
#pragma unroll
      for (int kt = 0; kt < 4; ++kt) {
        bf16x8 a = *(const bf16x8*)&g2_s[rt * 16 + lr][kt * 32 + lg * 8];
        acc = MFMA(a, bfr[kt], acc);
      }
      float v = 0.f;
#pragma unroll
      for (int q = 0; q < 4; ++q) {
        int jj = lg * 4 + q;
        float sg = 1.f / (1.f + __expf(-acc[q]));
        float g2v = bf2f(g2_s[rt * 16 + jj][o]);
        if (jj < KR) v += g2v * sg;
      }
      v += __shfl_xor(v, 16);
      v += __shfl_xor(v, 32);
      if (lane < 16) pool_s[rt][o] = f2bf(v);
    }
  }
  __syncthreads();

  {
    bf16x8 afr[4];
#pragma unroll
    for (int kt = 0; kt < 4; ++kt) afr[kt] = *(const bf16x8*)&pool_s[lr][kt * 32 + lg * 8];
#pragma unroll
    for (int cti = 0; cti < 4; ++cti) {
      int ct = w * 4 + cti;
      int o = ct * 16 + lr;
      f32x4 acc = {0.f, 0.f, 0.f, 0.f};
#pragma unroll
      for (int kt = 0; kt < 4; ++kt) {
        bf16x8 b = ((const bf16x8*)wpf)[(kt * 16 + ct) * 64 + lane];
        acc = MFMA(afr[kt], b, acc);
      }
      float scl = sp[o], bia = bp[o];
      if (lane < 16) {
#pragma unroll
        for (int q = 0; q < 4; ++q) {
          float v = fmaxf(acc[q] * scl + bia, 0.f);
          fout[(size_t)(pbase + q) * 512 + FOFF + o] = f2bf(v);
        }
      }
    }
  }
}

// ---------------- K4: out = relu(bn(f @ wf^T)) computed transposed ----------------
__global__ __launch_bounds__(256, 4) void k_final(
    const short* __restrict__ fbuf, const short* __restrict__ wff,
    const float* __restrict__ sf, const float* __restrict__ bfv,
    float* __restrict__ out) {
  __shared__ short b_s[256][72];
  int tid = threadIdx.x;
  int lane = tid & 63;
  int w = tid >> 6;
  int lr = lane & 15;
  int lg = lane >> 4;
  int ob = blockIdx.x;
  int p0 = blockIdx.y * 256;
  int rtg = ob * 4 + w;

  f32x4 acc[16];
#pragma unroll
  for (int ct = 0; ct < 16; ++ct) acc[ct] = (f32x4){0.f, 0.f, 0.f, 0.f};

  for (int kc = 0; kc < 512; kc += 64) {
    __syncthreads();
#pragma unroll
    for (int c = 0; c < 8; ++c) {
      int idx = c * 256 + tid;
      int row = idx >> 3, seg = idx & 7;
      *(float4*)&b_s[row][seg * 8] =
          *(const float4*)(fbuf + ((size_t)(p0 + row) * 512 + kc + seg * 8));
    }
    __syncthreads();
    int kt = kc >> 5;
    bf16x8 a0 = ((const bf16x8*)wff)[((size_t)(kt + 0) * 32 + rtg) * 64 + lane];
    bf16x8 a1 = ((const bf16x8*)wff)[((size_t)(kt + 1) * 32 + rtg) * 64 + lane];
#pragma unroll
    for (int ct = 0; ct < 16; ++ct) {
      bf16x8 bb0 = *(const bf16x8*)&b_s[ct * 16 + lr][lg * 8];
      bf16x8 bb1 = *(const bf16x8*)&b_s[ct * 16 + lr][32 + lg * 8];
      acc[ct] = MFMA(a0, bb0, acc[ct]);
      acc[ct] = MFMA(a1, bb1, acc[ct]);
    }
  }

  int b = p0 >> 11;
  int nb = p0 & (NN - 1);
#pragma unroll
  for (int q = 0; q < 4; ++q) {
    int o = rtg * 16 + lg * 4 + q;
    float scl = sf[o], bia = bfv[o];
#pragma unroll
    for (int ct = 0; ct < 16; ++ct) {
      int n = nb + ct * 16 + lr;
      float v = fmaxf(acc[ct][q] * scl + bia, 0.f);
      out[((size_t)b * 512 + o) * NN + n] = v;
    }
  }
}

extern "C" void kernel_launch(void* const* d_in, const int* in_sizes, int n_in,
                              void* d_out, int out_size, void* d_ws, size_t ws_size,
                              hipStream_t stream) {
  const float* x      = (const float*)d_in[0];
  const float* lw     = (const float*)d_in[1];
  const float* ls     = (const float*)d_in[2];
  const float* lb     = (const float*)d_in[3];
  const float* w1     = (const float*)d_in[4];
  const float* s1     = (const float*)d_in[5];
  const float* b1     = (const float*)d_in[6];
  const float* w2     = (const float*)d_in[7];
  const float* s2     = (const float*)d_in[8];
  const float* b2     = (const float*)d_in[9];
  const float* w3     = (const float*)d_in[10];
  const float* s3     = (const float*)d_in[11];
  const float* b3     = (const float*)d_in[12];
  const float* w4     = (const float*)d_in[13];
  const float* s4     = (const float*)d_in[14];
  const float* b4     = (const float*)d_in[15];
  const float* a1_att = (const float*)d_in[16];
  const float* a1_w   = (const float*)d_in[17];
  const float* a1_s   = (const float*)d_in[18];
  const float* a1_b   = (const float*)d_in[19];
  const float* a2_att = (const float*)d_in[20];
  const float* a2_w   = (const float*)d_in[21];
  const float* a2_s   = (const float*)d_in[22];
  const float* a2_b   = (const float*)d_in[23];
  const float* wf     = (const float*)d_in[24];
  const float* sf     = (const float*)d_in[25];
  const float* bf     = (const float*)d_in[26];
  float* out = (float*)d_out;

  char* ws = (char*)d_ws;
  float* h   = (float*)ws;                          ws += (size_t)BB * NN * 8 * 4;
  float* xx  = (float*)ws;                          ws += (size_t)BB * NN * 4;
  int* knn_idx = (int*)ws;                          ws += (size_t)BB * NN * 16 * 4;
  short* fbuf  = (short*)ws;                        ws += (size_t)BB * NN * 512 * 2;
  short* w1f   = (short*)ws;                        ws += 1 * 4 * 64 * 8 * 2;
  short* w3f   = (short*)ws;                        ws += 1 * 4 * 64 * 8 * 2;
  short* w2f   = (short*)ws;                        ws += 2 * 8 * 64 * 8 * 2;
  short* w4f   = (short*)ws;                        ws += 2 * 8 * 64 * 8 * 2;
  short* wa1f  = (short*)ws;                        ws += 4 * 8 * 64 * 8 * 2;
  short* wa2f  = (short*)ws;                        ws += 4 * 8 * 64 * 8 * 2;
  short* wp1f  = (short*)ws;                        ws += 4 * 16 * 64 * 8 * 2;
  short* wp2f  = (short*)ws;                        ws += 4 * 16 * 64 * 8 * 2;
  short* wff   = (short*)ws;                        ws += 16 * 32 * 64 * 8 * 2;

  k_pack<<<dim3(4),   dim3(64), 0, stream>>>(w1,     w1f, 64, 16);
  k_pack<<<dim3(4),   dim3(64), 0, stream>>>(w3,     w3f, 64, 16);
  k_pack<<<dim3(16),  dim3(64), 0, stream>>>(w2,     w2f, 128, 64);
  k_pack<<<dim3(16),  dim3(64), 0, stream>>>(w4,     w4f, 128, 64);
  k_pack<<<dim3(32),  dim3(64), 0, stream>>>(a1_att, wa1f, 128, 128);
  k_pack<<<dim3(32),  dim3(64), 0, stream>>>(a2_att, wa2f, 128, 128);
  k_pack<<<dim3(64),  dim3(64), 0, stream>>>(a1_w,   wp1f, 256, 128);
  k_pack<<<dim3(64),  dim3(64), 0, stream>>>(a2_w,   wp2f, 256, 128);
  k_pack<<<dim3(512), dim3(64), 0, stream>>>(wf,     wff, 512, 512);

  k_h<<<dim3((BB * NN + 255) / 256), dim3(256), 0, stream>>>(x, lw, ls, lb, h, xx);
  k_knn<<<dim3(512), dim3(128), 0, stream>>>(h, xx, knn_idx);
  k_branch<16, 0><<<dim3(BB * NN / 4), dim3(256), 0, stream>>>(
      h, knn_idx, w1f, s1, b1, w2f, s2, b2, wa1f, wp1f, a1_s, a1_b, fbuf);
  k_branch<12, 256><<<dim3(BB * NN / 4), dim3(256), 0, stream>>>(
      h, knn_idx, w3f, s3, b3, w4f, s4, b4, wa2f, wp2f, a2_s, a2_b, fbuf);
  k_final<<<dim3(8, 128), dim3(256), 0, stream>>>(fbuf, wff, sf, bf, out);
}

// Round 5
// 325.757 us; speedup vs baseline: 6.8067x; 1.2171x over previous
//
#include <hip/hip_runtime.h>
#include <hip/hip_bf16.h>
#include <math.h>

#define BB 16
#define NN 2048

typedef short bf16x8 __attribute__((ext_vector_type(8)));
typedef float f32x4 __attribute__((ext_vector_type(4)));

#define MFMA(a, b, c) __builtin_amdgcn_mfma_f32_16x16x32_bf16(a, b, c, 0, 0, 0)

static __device__ __forceinline__ short f2bf(float f) {
  union { float f; unsigned u; } v; v.f = f;
  unsigned r = v.u + 0x7fffu + ((v.u >> 16) & 1u);
  return (short)(r >> 16);
}
static __device__ __forceinline__ float bf2f(short s) {
  union { unsigned u; float f; } v; v.u = ((unsigned)(unsigned short)s) << 16;
  return v.f;
}

// ---------------- K1: h = relu(bn(conv1d(x))) ; xx = ||h||^2 ----------------
__global__ __launch_bounds__(256) void k_h(const float* __restrict__ x,
                                           const float* __restrict__ lw,
                                           const float* __restrict__ ls,
                                           const float* __restrict__ lb,
                                           float* __restrict__ h,
                                           float* __restrict__ xx) {
  int p = blockIdx.x * blockDim.x + threadIdx.x;
  if (p >= BB * NN) return;
  int b = p >> 11;
  int n = p & (NN - 1);
  const float* xb = x + (size_t)b * 3 * NN + n;
  float x0 = xb[0], x1 = xb[NN], x2 = xb[2 * NN];
  float hv[8];
  float ss = 0.f;
#pragma unroll
  for (int o = 0; o < 8; ++o) {
    float v = x0 * lw[o * 3 + 0] + x1 * lw[o * 3 + 1] + x2 * lw[o * 3 + 2];
    v = fmaxf(v * ls[o] + lb[o], 0.f);
    hv[o] = v;
    ss += v * v;  // same order as k_knn inner product -> self-dist exactly 0
  }
  float4* hp = (float4*)(h + (size_t)p * 8);
  hp[0] = make_float4(hv[0], hv[1], hv[2], hv[3]);
  hp[1] = make_float4(hv[4], hv[5], hv[6], hv[7]);
  xx[p] = ss;
}

// ---------------- K2: kNN top-16. 8 slices/query, wave-private staging, no scan barriers ----
// Block: 512 thr = 8 waves over the same 64 queries; wave w scans slice [w*256,(w+1)*256).
// Per-thread exact top-16 (sorted u64 keys) + LDS stack (cap 8) + bitonic flush.
// 3-level pairwise merge tree at the end. Exact jax tie order (desc value, asc index).
__global__ __launch_bounds__(512, 4) void k_knn(const float* __restrict__ h,
                                                const float* __restrict__ xx,
                                                int* __restrict__ knn_idx) {
  __shared__ __align__(16) unsigned char smem[55296];
  float4* sh4 = (float4*)smem;                                    // [8][64][2]
  float* sxx = (float*)(smem + 16384);                            // [8][64]
  unsigned long long* stkb = (unsigned long long*)(smem + 18432); // [512][9]

  int tid = threadIdx.x;
  int lane = tid & 63;
  int w = tid >> 6;
  int blk = blockIdx.x;            // 512 blocks
  int b = blk >> 5;                // 32 blocks per batch
  int qloc = ((blk & 31) << 6) + lane;
  int p = (b << 11) + qloc;
  const float* hb = h + ((size_t)b << 11) * 8;
  const float* xxb = xx + ((size_t)b << 11);

  const float4* qp = (const float4*)(hb + (size_t)qloc * 8);
  float4 q0 = qp[0], q1 = qp[1];
  float xq = xxb[qloc];

  unsigned long long* stkrow = stkb + tid * 9;
  unsigned long long a[16];        // sorted ascending; a[0] = current 16th best
#pragma unroll
  for (int i = 0; i < 16; ++i) a[i] = 0ULL;
  int cnt = 0;

  auto eval = [&](int s, int mg) -> unsigned long long {
    float4 a0 = sh4[(w * 64 + s) * 2 + 0];
    float4 a1 = sh4[(w * 64 + s) * 2 + 1];
    float xm = sxx[w * 64 + s];
    float inner = q0.x * a0.x + q0.y * a0.y + q0.z * a0.z + q0.w * a0.w +
                  q1.x * a1.x + q1.y * a1.y + q1.z * a1.z + q1.w * a1.w;
    float d = 2.f * inner - xq - xm;
    unsigned uu = __float_as_uint(d);
    unsigned key = ((int)uu >= 0) ? (uu | 0x80000000u) : ~uu;
    return ((unsigned long long)key << 32) | (unsigned)(NN - 1 - mg);
  };

  auto flush = [&]() {
    unsigned long long c[8];
#pragma unroll
    for (int j = 0; j < 8; ++j) {
      unsigned long long v = stkrow[j];
      c[j] = (j < cnt) ? v : 0ULL;
    }
    cnt = 0;
    // bitonic sort 8 ascending
#pragma unroll
    for (int k = 2; k <= 8; k <<= 1)
#pragma unroll
      for (int j = k >> 1; j > 0; j >>= 1)
#pragma unroll
        for (int i = 0; i < 8; ++i) {
          int l = i ^ j;
          if (l > i) {
            bool up = ((i & k) == 0);
            unsigned long long xi = c[i], xl = c[l];
            bool sw = up ? (xi > xl) : (xi < xl);
            if (sw) { c[i] = xl; c[l] = xi; }
          }
        }
    // merge sorted-8 into sorted-16 (keep top 16)
    unsigned long long m[16];
#pragma unroll
    for (int i = 0; i < 16; ++i) {
      unsigned long long bi = (i < 8) ? c[7 - i] : 0ULL;
      m[i] = (a[i] > bi) ? a[i] : bi;
    }
#pragma unroll
    for (int j = 8; j > 0; j >>= 1)
#pragma unroll
      for (int i = 0; i < 16; ++i) {
        int l = i ^ j;
        if (l > i && m[i] > m[l]) { unsigned long long t = m[i]; m[i] = m[l]; m[l] = t; }
      }
#pragma unroll
    for (int i = 0; i < 16; ++i) a[i] = m[i];
  };

  int sbase = w * 256;             // this wave's slice base
  // prefetch chunk 0 (lane <-> candidate, wave-private region: no block barriers)
  float4 r0, r1;
  float rx;
  {
    const float* cp = hb + (size_t)(sbase + lane) * 8;
    r0 = *(const float4*)cp;
    r1 = *(const float4*)(cp + 4);
    rx = xxb[sbase + lane];
  }
  for (int c2 = 0; c2 < 4; ++c2) {
    sh4[(w * 64 + lane) * 2 + 0] = r0;
    sh4[(w * 64 + lane) * 2 + 1] = r1;
    sxx[w * 64 + lane] = rx;
    if (c2 < 3) {
      const float* cp = hb + (size_t)(sbase + (c2 + 1) * 64 + lane) * 8;
      r0 = *(const float4*)cp;
      r1 = *(const float4*)(cp + 4);
      rx = xxb[sbase + (c2 + 1) * 64 + lane];
    }
    int mg0 = sbase + c2 * 64;
    int s = 0;
    if (c2 == 0) {
      // warm start: sort the first 16 candidates directly into a[]
      unsigned long long cc[16];
#pragma unroll
      for (int j = 0; j < 16; ++j) cc[j] = eval(j, mg0 + j);
#pragma unroll
      for (int k = 2; k <= 16; k <<= 1)
#pragma unroll
        for (int j = k >> 1; j > 0; j >>= 1)
#pragma unroll
          for (int i = 0; i < 16; ++i) {
            int l = i ^ j;
            if (l > i) {
              bool up = ((i & k) == 0);
              unsigned long long xi = cc[i], xl = cc[l];
              bool sw = up ? (xi > xl) : (xi < xl);
              if (sw) { cc[i] = xl; cc[l] = xi; }
            }
          }
#pragma unroll
      for (int i = 0; i < 16; ++i) a[i] = cc[i];
      s = 16;
    }
    for (; s < 64; s += 4) {
#pragma unroll
      for (int u = 0; u < 4; ++u) {
        unsigned long long key64 = eval(s + u, mg0 + s + u);
        if (key64 > a[0]) { stkrow[cnt] = key64; cnt++; }
      }
      if (__any(cnt >= 5)) flush();
    }
  }
  if (__any(cnt > 0)) flush();

  // ---- merge tree: 8 lists/query -> 1 (exact; reuses scan LDS, stacks dead) ----
  unsigned long long* M1 = (unsigned long long*)smem;             // [4][64][17]
  unsigned long long* M2 = (unsigned long long*)(smem + 36864);   // [2][64][17]
  unsigned long long* M3 = (unsigned long long*)smem;             // [64][17]

  auto mergeLds = [&](const unsigned long long* src) {
    unsigned long long m[16];
#pragma unroll
    for (int i = 0; i < 16; ++i) {
      unsigned long long bi = src[15 - i];
      m[i] = (a[i] > bi) ? a[i] : bi;
    }
#pragma unroll
    for (int j = 8; j > 0; j >>= 1)
#pragma unroll
      for (int i = 0; i < 16; ++i) {
        int l = i ^ j;
        if (l > i && m[i] > m[l]) { unsigned long long t = m[i]; m[i] = m[l]; m[l] = t; }
      }
#pragma unroll
    for (int i = 0; i < 16; ++i) a[i] = m[i];
  };

  __syncthreads();
  if (w >= 4) {
#pragma unroll
    for (int i = 0; i < 16; ++i) M1[((w - 4) * 64 + lane) * 17 + i] = a[i];
  }
  __syncthreads();
  if (w < 4) mergeLds(&M1[(w * 64 + lane) * 17]);
  __syncthreads();
  if (w == 2 || w == 3) {
#pragma unroll
    for (int i = 0; i < 16; ++i) M2[((w - 2) * 64 + lane) * 17 + i] = a[i];
  }
  __syncthreads();
  if (w < 2) mergeLds(&M2[(w * 64 + lane) * 17]);
  __syncthreads();
  if (w == 1) {
#pragma unroll
    for (int i = 0; i < 16; ++i) M3[lane * 17 + i] = a[i];
  }
  __syncthreads();
  if (w == 0) {
    mergeLds(&M3[lane * 17]);
    int ids[16];
#pragma unroll
    for (int r = 0; r < 16; ++r)
      ids[r] = (NN - 1) - (int)(unsigned)(a[15 - r] & 0xFFFFFFFFULL);
    int4* op = (int4*)(knn_idx + (size_t)p * 16);
    op[0] = make_int4(ids[0], ids[1], ids[2], ids[3]);
    op[1] = make_int4(ids[4], ids[5], ids[6], ids[7]);
    op[2] = make_int4(ids[8], ids[9], ids[10], ids[11]);
    op[3] = make_int4(ids[12], ids[13], ids[14], ids[15]);
  }
}

// ---------------- unified weight pack: fp32 (O,C) -> bf16 MFMA B-fragment order ----------------
// dst[(kt*NCT + ct)*64 + lane][i] = w[col][k], col = ct*16+(lane&15), k = kt*32+(lane>>4)*8+i
__global__ __launch_bounds__(64) void k_packall(
    const float* __restrict__ w1, const float* __restrict__ w3,
    const float* __restrict__ w2, const float* __restrict__ w4,
    const float* __restrict__ a1_att, const float* __restrict__ a2_att,
    const float* __restrict__ a1_w, const float* __restrict__ a2_w,
    const float* __restrict__ wf,
    short* __restrict__ w1f, short* __restrict__ w3f,
    short* __restrict__ w2f, short* __restrict__ w4f,
    short* __restrict__ wa1f, short* __restrict__ wa2f,
    short* __restrict__ wp1f, short* __restrict__ wp2f,
    short* __restrict__ wff) {
  int bb = blockIdx.x;
  const float* src;
  short* dst;
  int O, C, base;
  if (bb < 4)        { src = w1;     dst = w1f;  O = 64;  C = 16;  base = 0; }
  else if (bb < 8)   { src = w3;     dst = w3f;  O = 64;  C = 16;  base = 4; }
  else if (bb < 24)  { src = w2;     dst = w2f;  O = 128; C = 64;  base = 8; }
  else if (bb < 40)  { src = w4;     dst = w4f;  O = 128; C = 64;  base = 24; }
  else if (bb < 72)  { src = a1_att; dst = wa1f; O = 128; C = 128; base = 40; }
  else if (bb < 104) { src = a2_att; dst = wa2f; O = 128; C = 128; base = 72; }
  else if (bb < 168) { src = a1_w;   dst = wp1f; O = 256; C = 128; base = 104; }
  else if (bb < 232) { src = a2_w;   dst = wp2f; O = 256; C = 128; base = 168; }
  else               { src = wf;     dst = wff;  O = 512; C = 512; base = 232; }
  int blk = bb - base;
  int NCT = O >> 4;
  int ct = blk % NCT;
  int kt = blk / NCT;
  int l = threadIdx.x;
  int col = ct * 16 + (l & 15);
  bf16x8 v;
#pragma unroll
  for (int i = 0; i < 8; ++i) {
    int k = kt * 32 + ((l >> 4) << 3) + i;
    v[i] = (k < C) ? f2bf(src[(size_t)col * C + k]) : (short)0;
  }
  ((bf16x8*)dst)[(size_t)blk * 64 + l] = v;
}

// ---------------- K3: fused edge->conv1->conv2->att-score->pool->att-conv (MFMA) ----------------
template <int KR, int FOFF>
__global__ __launch_bounds__(256, 4) void k_branch(
    const float* __restrict__ h, const int* __restrict__ knn_idx,
    const short* __restrict__ w1f, const float* __restrict__ s1, const float* __restrict__ b1,
    const short* __restrict__ w2f, const float* __restrict__ s2, const float* __restrict__ b2,
    const short* __restrict__ wattf,
    const short* __restrict__ wpf, const float* __restrict__ sp, const float* __restrict__ bp,
    short* __restrict__ fout) {
  __shared__ short e_s[64][48];
  __shared__ short g1_s[64][72];
  __shared__ short g2_s[64][136];
  __shared__ short pool_s[16][136];

  int tid = threadIdx.x;
  int lane = tid & 63;
  int w = tid >> 6;
  int lr = lane & 15;
  int lg = lane >> 4;
  int pbase = blockIdx.x * 4;
  const float* hb = h + ((size_t)(pbase & ~(NN - 1))) * 8;

  if (tid < 64) {
    int t = tid >> 4, j = tid & 15;
    int p = pbase + t;
    const float* cp = h + (size_t)p * 8;
    bool real = (j < KR);
    int id = real ? knn_idx[(size_t)p * 16 + j] : 0;
    const float* np_ = hb + (size_t)id * 8;
#pragma unroll
    for (int c = 0; c < 8; ++c) {
      float cv = cp[c], nv = np_[c];
      e_s[tid][c] = real ? f2bf(nv - cv) : (short)0;
      e_s[tid][8 + c] = real ? f2bf(cv) : (short)0;
      e_s[tid][16 + c] = 0;
      e_s[tid][24 + c] = 0;
    }
  }
  __syncthreads();

  {
    int ct = w;
    int o = ct * 16 + lr;
    bf16x8 bfrag = ((const bf16x8*)w1f)[ct * 64 + lane];
    float scl = s1[o], bia = b1[o];
#pragma unroll
    for (int rt = 0; rt < 4; ++rt) {
      bf16x8 af = *(const bf16x8*)&e_s[rt * 16 + lr][lg * 8];
      f32x4 acc = {0.f, 0.f, 0.f, 0.f};
      acc = MFMA(af, bfrag, acc);
#pragma unroll
      for (int q = 0; q < 4; ++q) {
        int r = rt * 16 + lg * 4 + q;
        g1_s[r][o] = f2bf(fmaxf(acc[q] * scl + bia, 0.f));
      }
    }
  }
  __syncthreads();

#pragma unroll
  for (int cti = 0; cti < 2; ++cti) {
    int ct = w * 2 + cti;
    int o = ct * 16 + lr;
    bf16x8 bf0 = ((const bf16x8*)w2f)[(0 * 8 + ct) * 64 + lane];
    bf16x8 bf1 = ((const bf16x8*)w2f)[(1 * 8 + ct) * 64 + lane];
    float scl = s2[o], bia = b2[o];
#pragma unroll
    for (int rt = 0; rt < 4; ++rt) {
      bf16x8 a0 = *(const bf16x8*)&g1_s[rt * 16 + lr][lg * 8];
      bf16x8 a1 = *(const bf16x8*)&g1_s[rt * 16 + lr][32 + lg * 8];
      f32x4 acc = {0.f, 0.f, 0.f, 0.f};
      acc = MFMA(a0, bf0, acc);
      acc = MFMA(a1, bf1, acc);
#pragma unroll
      for (int q = 0; q < 4; ++q) {
        int r = rt * 16 + lg * 4 + q;
        g2_s[r][o] = f2bf(fmaxf(acc[q] * scl + bia, 0.f));
      }
    }
  }
  __syncthreads();

#pragma unroll
  for (int cti = 0; cti < 2; ++cti) {
    int ct = w * 2 + cti;
    int o = ct * 16 + lr;
    bf16x8 bfr[4];
#pragma unroll
    for (int kt = 0; kt < 4; ++kt) bfr[kt] = ((const bf16x8*)wattf)[(kt * 8 + ct) * 64 + lane];
#pragma unroll
    for (int rt = 0; rt < 4; ++rt) {
      f32x4 acc = {0.f, 0.f, 0.f, 0.f};
#pragma unroll
      for (int kt = 0; kt < 4; ++kt) {
        bf16x8 a = *(const bf16x8*)&g2_s[rt * 16 + lr][kt * 32 + lg * 8];
        acc = MFMA(a, bfr[kt], acc);
      }
      float v = 0.f;
#pragma unroll
      for (int q = 0; q < 4; ++q) {
        int jj = lg * 4 + q;
        float sg = 1.f / (1.f + __expf(-acc[q]));
        float g2v = bf2f(g2_s[rt * 16 + jj][o]);
        if (jj < KR) v += g2v * sg;
      }
      v += __shfl_xor(v, 16);
      v += __shfl_xor(v, 32);
      if (lane < 16) pool_s[rt][o] = f2bf(v);
    }
  }
  __syncthreads();

  {
    bf16x8 afr[4];
#pragma unroll
    for (int kt = 0; kt < 4; ++kt) afr[kt] = *(const bf16x8*)&pool_s[lr][kt * 32 + lg * 8];
#pragma unroll
    for (int cti = 0; cti < 4; ++cti) {
      int ct = w * 4 + cti;
      int o = ct * 16 + lr;
      f32x4 acc = {0.f, 0.f, 0.f, 0.f};
#pragma unroll
      for (int kt = 0; kt < 4; ++kt) {
        bf16x8 b = ((const bf16x8*)wpf)[(kt * 16 + ct) * 64 + lane];
        acc = MFMA(afr[kt], b, acc);
      }
      float scl = sp[o], bia = bp[o];
      if (lane < 16) {
#pragma unroll
        for (int q = 0; q < 4; ++q) {
          float v = fmaxf(acc[q] * scl + bia, 0.f);
          fout[(size_t)(pbase + q) * 512 + FOFF + o] = f2bf(v);
        }
      }
    }
  }
}

// ---------------- K4: out = relu(bn(f @ wf^T)) computed transposed ----------------
__global__ __launch_bounds__(256, 4) void k_final(
    const short* __restrict__ fbuf, const short* __restrict__ wff,
    const float* __restrict__ sf, const float* __restrict__ bfv,
    float* __restrict__ out) {
  __shared__ short b_s[256][72];
  int tid = threadIdx.x;
  int lane = tid & 63;
  int w = tid >> 6;
  int lr = lane & 15;
  int lg = lane >> 4;
  int ob = blockIdx.x;
  int p0 = blockIdx.y * 256;
  int rtg = ob * 4 + w;

  f32x4 acc[16];
#pragma unroll
  for (int ct = 0; ct < 16; ++ct) acc[ct] = (f32x4){0.f, 0.f, 0.f, 0.f};

  for (int kc = 0; kc < 512; kc += 64) {
    __syncthreads();
#pragma unroll
    for (int c = 0; c < 8; ++c) {
      int idx = c * 256 + tid;
      int row = idx >> 3, seg = idx & 7;
      *(float4*)&b_s[row][seg * 8] =
          *(const float4*)(fbuf + ((size_t)(p0 + row) * 512 + kc + seg * 8));
    }
    __syncthreads();
    int kt = kc >> 5;
    bf16x8 a0 = ((const bf16x8*)wff)[((size_t)(kt + 0) * 32 + rtg) * 64 + lane];
    bf16x8 a1 = ((const bf16x8*)wff)[((size_t)(kt + 1) * 32 + rtg) * 64 + lane];
#pragma unroll
    for (int ct = 0; ct < 16; ++ct) {
      bf16x8 bb0 = *(const bf16x8*)&b_s[ct * 16 + lr][lg * 8];
      bf16x8 bb1 = *(const bf16x8*)&b_s[ct * 16 + lr][32 + lg * 8];
      acc[ct] = MFMA(a0, bb0, acc[ct]);
      acc[ct] = MFMA(a1, bb1, acc[ct]);
    }
  }

  int b = p0 >> 11;
  int nb = p0 & (NN - 1);
#pragma unroll
  for (int q = 0; q < 4; ++q) {
    int o = rtg * 16 + lg * 4 + q;
    float scl = sf[o], bia = bfv[o];
#pragma unroll
    for (int ct = 0; ct < 16; ++ct) {
      int n = nb + ct * 16 + lr;
      float v = fmaxf(acc[ct][q] * scl + bia, 0.f);
      out[((size_t)b * 512 + o) * NN + n] = v;
    }
  }
}

extern "C" void kernel_launch(void* const* d_in, const int* in_sizes, int n_in,
                              void* d_out, int out_size, void* d_ws, size_t ws_size,
                              hipStream_t stream) {
  const float* x      = (const float*)d_in[0];
  const float* lw     = (const float*)d_in[1];
  const float* ls     = (const float*)d_in[2];
  const float* lb     = (const float*)d_in[3];
  const float* w1     = (const float*)d_in[4];
  const float* s1     = (const float*)d_in[5];
  const float* b1     = (const float*)d_in[6];
  const float* w2     = (const float*)d_in[7];
  const float* s2     = (const float*)d_in[8];
  const float* b2     = (const float*)d_in[9];
  const float* w3     = (const float*)d_in[10];
  const float* s3     = (const float*)d_in[11];
  const float* b3     = (const float*)d_in[12];
  const float* w4     = (const float*)d_in[13];
  const float* s4     = (const float*)d_in[14];
  const float* b4     = (const float*)d_in[15];
  const float* a1_att = (const float*)d_in[16];
  const float* a1_w   = (const float*)d_in[17];
  const float* a1_s   = (const float*)d_in[18];
  const float* a1_b   = (const float*)d_in[19];
  const float* a2_att = (const float*)d_in[20];
  const float* a2_w   = (const float*)d_in[21];
  const float* a2_s   = (const float*)d_in[22];
  const float* a2_b   = (const float*)d_in[23];
  const float* wf     = (const float*)d_in[24];
  const float* sf     = (const float*)d_in[25];
  const float* bf     = (const float*)d_in[26];
  float* out = (float*)d_out;

  char* ws = (char*)d_ws;
  float* h   = (float*)ws;                          ws += (size_t)BB * NN * 8 * 4;
  float* xx  = (float*)ws;                          ws += (size_t)BB * NN * 4;
  int* knn_idx = (int*)ws;                          ws += (size_t)BB * NN * 16 * 4;
  short* fbuf  = (short*)ws;                        ws += (size_t)BB * NN * 512 * 2;
  short* w1f   = (short*)ws;                        ws += 1 * 4 * 64 * 8 * 2;
  short* w3f   = (short*)ws;                        ws += 1 * 4 * 64 * 8 * 2;
  short* w2f   = (short*)ws;                        ws += 2 * 8 * 64 * 8 * 2;
  short* w4f   = (short*)ws;                        ws += 2 * 8 * 64 * 8 * 2;
  short* wa1f  = (short*)ws;                        ws += 4 * 8 * 64 * 8 * 2;
  short* wa2f  = (short*)ws;                        ws += 4 * 8 * 64 * 8 * 2;
  short* wp1f  = (short*)ws;                        ws += 4 * 16 * 64 * 8 * 2;
  short* wp2f  = (short*)ws;                        ws += 4 * 16 * 64 * 8 * 2;
  short* wff   = (short*)ws;                        ws += 16 * 32 * 64 * 8 * 2;

  k_packall<<<dim3(744), dim3(64), 0, stream>>>(
      w1, w3, w2, w4, a1_att, a2_att, a1_w, a2_w, wf,
      w1f, w3f, w2f, w4f, wa1f, wa2f, wp1f, wp2f, wff);

  k_h<<<dim3((BB * NN + 255) / 256), dim3(256), 0, stream>>>(x, lw, ls, lb, h, xx);
  k_knn<<<dim3(512), dim3(512), 0, stream>>>(h, xx, knn_idx);
  k_branch<16, 0><<<dim3(BB * NN / 4), dim3(256), 0, stream>>>(
      h, knn_idx, w1f, s1, b1, w2f, s2, b2, wa1f, wp1f, a1_s, a1_b, fbuf);
  k_branch<12, 256><<<dim3(BB * NN / 4), dim3(256), 0, stream>>>(
      h, knn_idx, w3f, s3, b3, w4f, s4, b4, wa2f, wp2f, a2_s, a2_b, fbuf);
  k_final<<<dim3(8, 128), dim3(256), 0, stream>>>(fbuf, wff, sf, bf, out);
}